// Round 1
// baseline (4003.036 us; speedup 1.0000x reference)
//
#include <hip/hip_runtime.h>
#include <cstddef>

#define NN 883
#define BB 64
#define TT 12
#define EMB 10
#define KPAD 896  // node dim padded to multiple of 128

typedef short short8 __attribute__((ext_vector_type(8)));
typedef _Float16 half8 __attribute__((ext_vector_type(8)));
typedef float f32x4 __attribute__((ext_vector_type(4)));

__device__ __forceinline__ void split_f16(float v, _Float16* hp, _Float16* lp) {
  _Float16 h = (_Float16)v;
  *hp = h;
  *lp = (_Float16)(v - (float)h);
}

// -------- adjacency: A = softmax(relu(E E^T), axis=1), emitted as f16 hi/lo --
__global__ __launch_bounds__(256) void adj_kernel(const float* __restrict__ E,
                                                  _Float16* __restrict__ Ah,
                                                  _Float16* __restrict__ Al) {
  const int n = blockIdx.x;
  const int tid = threadIdx.x;
  __shared__ float sE[EMB];
  __shared__ float sred[256];
  if (tid < EMB) sE[tid] = E[n * EMB + tid];
  __syncthreads();
  float d[4];
  float lmax = 0.0f;
#pragma unroll
  for (int q = 0; q < 4; ++q) {
    int m = tid + q * 256;
    d[q] = 0.0f;
    if (m < NN) {
      float s = 0.0f;
#pragma unroll
      for (int e = 0; e < EMB; ++e) s += sE[e] * E[m * EMB + e];
      d[q] = fmaxf(s, 0.0f);
      lmax = fmaxf(lmax, d[q]);
    }
  }
  sred[tid] = lmax;
  __syncthreads();
  for (int s = 128; s > 0; s >>= 1) {
    if (tid < s) sred[tid] = fmaxf(sred[tid], sred[tid + s]);
    __syncthreads();
  }
  const float mx = sred[0];
  __syncthreads();
  float lsum = 0.0f;
#pragma unroll
  for (int q = 0; q < 4; ++q) {
    int m = tid + q * 256;
    if (m < NN) {
      d[q] = expf(d[q] - mx);
      lsum += d[q];
    }
  }
  sred[tid] = lsum;
  __syncthreads();
  for (int s = 128; s > 0; s >>= 1) {
    if (tid < s) sred[tid] += sred[tid + s];
    __syncthreads();
  }
  const float inv = 1.0f / sred[0];
#pragma unroll
  for (int q = 0; q < 4; ++q) {
    int m = tid + q * 256;
    if (m < KPAD) {
      float v = (m < NN) ? d[q] * inv : 0.0f;
      split_f16(v, &Ah[(size_t)n * KPAD + m], &Al[(size_t)n * KPAD + m]);
    }
  }
}

// -------- 3-term split-f16 MFMA GEMM; output written as split f16 ------------
__global__ __launch_bounds__(256) void mfma_gemm3(const _Float16* __restrict__ Ah,
                                                  const _Float16* __restrict__ Al,
                                                  const _Float16* __restrict__ Xh,
                                                  const _Float16* __restrict__ Xl,
                                                  _Float16* __restrict__ Gh,
                                                  _Float16* __restrict__ Gl, int L) {
  __shared__ _Float16 sA[2][128][40];
  __shared__ _Float16 sX[2][4][128][8];
  const int tid = threadIdx.x;
  const int lane = tid & 63;
  const int wid = tid >> 6;
  const int wm = (wid >> 1) * 64, wn = (wid & 1) * 64;
  const int bm = blockIdx.y * 128;
  const int bl = blockIdx.x * 128;
  const int l15 = lane & 15, l4 = lane >> 4;

  f32x4 acc[4][4] = {};

  const int xlp = (tid & 63) * 2;
  const int xko = tid >> 6;

  for (int k0 = 0; k0 < KPAD; k0 += 32) {
    __syncthreads();
#pragma unroll
    for (int p = 0; p < 2; ++p) {
      int i = tid + p * 256;
      int m = i >> 2, k8 = (i & 3) * 8;
      *(half8*)&sA[0][m][k8] = *(const half8*)&Ah[(size_t)(bm + m) * KPAD + k0 + k8];
      *(half8*)&sA[1][m][k8] = *(const half8*)&Al[(size_t)(bm + m) * KPAD + k0 + k8];
    }
    {
      int gl = bl + xlp;
      int kb = k0 + xko * 8;
#pragma unroll
      for (int buf = 0; buf < 2; ++buf) {
        const _Float16* Xp = buf ? Xl : Xh;
        unsigned int v[8];
#pragma unroll
        for (int j = 0; j < 8; ++j)
          v[j] = *(const unsigned int*)&Xp[(size_t)(kb + j) * L + gl];
        short8 lo, hi;
#pragma unroll
        for (int j = 0; j < 8; ++j) {
          lo[j] = (short)(v[j] & 0xFFFFu);
          hi[j] = (short)(v[j] >> 16);
        }
        *(short8*)&sX[buf][xko][xlp][0] = lo;
        *(short8*)&sX[buf][xko][xlp + 1][0] = hi;
      }
    }
    __syncthreads();
    half8 afh[4], afl[4], bfh[4], bfl[4];
#pragma unroll
    for (int mi = 0; mi < 4; ++mi) {
      afh[mi] = *(half8*)&sA[0][wm + mi * 16 + l15][l4 * 8];
      afl[mi] = *(half8*)&sA[1][wm + mi * 16 + l15][l4 * 8];
    }
#pragma unroll
    for (int ni = 0; ni < 4; ++ni) {
      bfh[ni] = *(half8*)&sX[0][l4][wn + ni * 16 + l15][0];
      bfl[ni] = *(half8*)&sX[1][l4][wn + ni * 16 + l15][0];
    }
#pragma unroll
    for (int mi = 0; mi < 4; ++mi)
#pragma unroll
      for (int ni = 0; ni < 4; ++ni) {
        acc[mi][ni] = __builtin_amdgcn_mfma_f32_16x16x32_f16(afh[mi], bfh[ni],
                                                             acc[mi][ni], 0, 0, 0);
        acc[mi][ni] = __builtin_amdgcn_mfma_f32_16x16x32_f16(afh[mi], bfl[ni],
                                                             acc[mi][ni], 0, 0, 0);
        acc[mi][ni] = __builtin_amdgcn_mfma_f32_16x16x32_f16(afl[mi], bfh[ni],
                                                             acc[mi][ni], 0, 0, 0);
      }
  }
#pragma unroll
  for (int mi = 0; mi < 4; ++mi) {
    int row0 = bm + wm + mi * 16 + l4 * 4;
#pragma unroll
    for (int ni = 0; ni < 4; ++ni) {
      int col = bl + wn + ni * 16 + l15;
#pragma unroll
      for (int r = 0; r < 4; ++r) {
        int row = row0 + r;
        if (row < NN)
          split_f16(acc[mi][ni][r], &Gh[(size_t)row * L + col],
                    &Gl[(size_t)row * L + col]);
      }
    }
  }
}

// -------- build Xs: all 12 steps' x, octet-major [n][t][b][8] (j=0 only) -----
__global__ __launch_bounds__(256) void srcall_kernel(const float* __restrict__ src,
                                                     _Float16* __restrict__ Xsh,
                                                     _Float16* __restrict__ Xsl) {
  int i = blockIdx.x * 256 + threadIdx.x;
  if (i >= NN * BB * TT) return;
  int t = i % TT;
  int nb = i / TT;
  int b = nb & 63, n = nb >> 6;
  float v = src[((size_t)b * TT + t) * NN + n];
  size_t idx = (size_t)n * (TT * 512) + (size_t)t * 512 + (size_t)b * 8;
  split_f16(v, &Xsh[idx], &Xsl[idx]);
}

// -------- one-time per-node weight gen (t-invariant!) ------------------------
// Writes split-f16 weights in exactly the gconv LDS tile layout:
// per (node n, o-chunk oc): [KOW][OW][8] halves, flat 16B-aligned.
template <int CS, int CIN, int XSPLIT, int OW, int COUT>
__global__ __launch_bounds__(256) void wgen_pre(const float* __restrict__ E,
                                                const float* __restrict__ wpool,
                                                _Float16* __restrict__ Wh,
                                                _Float16* __restrict__ Wl) {
  constexpr int C = COUT / OW;
  constexpr int KD = 2 * CS;
  constexpr int KOW = KD / 8;
  const int bid = blockIdx.x;
  const int n = bid / C;
  const int oc = bid % C;
  if (n >= NN) return;
  const int och = oc * OW;
  const int tid = threadIdx.x;
  __shared__ float sE[EMB];
  if (tid < EMB) sE[tid] = E[n * EMB + tid];
  __syncthreads();
  _Float16* bh = Wh + ((size_t)n * C + oc) * ((size_t)KOW * OW * 8);
  _Float16* bl = Wl + ((size_t)n * C + oc) * ((size_t)KOW * OW * 8);
  const int o = tid & (OW - 1);
  for (int ko = tid / OW; ko < KOW; ko += 256 / OW) {
    half8 hv, lv;
#pragma unroll
    for (int j = 0; j < 8; ++j) {
      const int k = ko * 8 + j;
      const int kk = (k >= CS) ? 1 : 0;
      const int kc = k - kk * CS;
      int ii;
      if (CS == CIN) ii = kc;
      else ii = (kc == 0) ? 0 : ((kc >= XSPLIT) ? kc - XSPLIT + 1 : -1);
      float w = 0.0f;
      if (ii >= 0) {
        const float* wp = wpool + ((size_t)kk * CIN + ii) * COUT + och + o;
#pragma unroll
        for (int d = 0; d < EMB; ++d)
          w += sE[d] * wp[(size_t)d * (2 * CIN * COUT)];
      }
      _Float16 hh = (_Float16)w;
      hv[j] = hh;
      lv[j] = (_Float16)(w - (float)hh);
    }
    *(half8*)&bh[((size_t)ko * OW + o) * 8] = hv;
    *(half8*)&bl[((size_t)ko * OW + o) * 8] = lv;
  }
}

// -------- fused per-node gconv: W from precompute (or fused gen) + MFMA ------
// All operand buffers octet-major per node: [n][ko][b][8], channel = ko*8+j.
// K regions: [0,XSPLIT) IX; [XSPLIT,CS) IZ; [CS,CS+XSPLIT) DX; [CS+XSPLIT,KD) DZ.
// OW: o-tile width per block; C = COUT/OW o-chunks per node.
// 1D grid with XCD swizzle: id = (n%8) + 8*(C*(n/8) + oc) puts all C chunks
// of node n on the SAME XCD so the node's X/G rows are fetched once per L2.
// GATE: o_global<64 -> z-half writes z*h into XA (=Xz); else r -> ZRout.
// !GATE: GRU update, writes h-state + split-f16 h into XA.
// PWh/PWl: precomputed split-f16 weights (wgen_pre layout); nullptr -> fused gen.
template <int CS, int CIN, int XSPLIT, int OW, bool GATE>
__global__ __launch_bounds__(256) void gconv_fused(
    const _Float16* __restrict__ IXh, const _Float16* __restrict__ IXl, int sIX, int oIX,
    const _Float16* __restrict__ IZh, const _Float16* __restrict__ IZl, int sIZ, int oIZ,
    const _Float16* __restrict__ DXh, const _Float16* __restrict__ DXl, int sDX, int oDX,
    const _Float16* __restrict__ DZh, const _Float16* __restrict__ DZl, int sDZ, int oDZ,
    const float* __restrict__ E, const float* __restrict__ wpool,
    const float* __restrict__ bpool, const float* __restrict__ ZRin,
    float* __restrict__ hstate, float* __restrict__ ZRout,
    _Float16* __restrict__ XAh, _Float16* __restrict__ XAl, int csA, int cbA,
    const _Float16* __restrict__ PWh, const _Float16* __restrict__ PWl) {
  constexpr int COUT = GATE ? 128 : 64;
  constexpr int C = COUT / OW;         // o-chunks per node
  constexpr int KD = 2 * CS;
  constexpr int KP = (KD + 31) & ~31;  // 160 / 256 (MFMA loop extent)
  constexpr int KOW = KD / 8;          // 18 / 32 (W octets actually stored)
  constexpr int NT = OW / 32;          // n-tiles per wave
  // XCD swizzle decode
  const int bid = blockIdx.x;
  const int xcd = bid & 7;
  const int rest = bid >> 3;
  const int oc = rest % C;
  const int nq = rest / C;
  const int n = nq * 8 + xcd;
  if (n >= NN) return;
  const int och = oc * OW;
  const int tid = threadIdx.x;
  const int lane = tid & 63, wid = tid >> 6;
  const int wm = (wid & 1) * 32;
  const int wn = (wid >> 1) * (OW / 2);
  const int l15 = lane & 15, l4 = lane >> 4;

  __shared__ float sE[EMB];
  __shared__ float sB[OW];
  __shared__ _Float16 sWh[KOW * OW * 8];
  __shared__ _Float16 sWl[KOW * OW * 8];

  if (tid < EMB) sE[tid] = E[n * EMB + tid];
  __syncthreads();

  // ---- W: stream precomputed tile, or fused gen fallback --------------------
  if (PWh != nullptr) {
    const size_t wbase = ((size_t)n * C + oc) * ((size_t)KOW * OW * 8);
    for (int i = tid; i < KOW * OW; i += 256) {
      *(half8*)&sWh[(size_t)i * 8] = *(const half8*)&PWh[wbase + (size_t)i * 8];
      *(half8*)&sWl[(size_t)i * 8] = *(const half8*)&PWl[wbase + (size_t)i * 8];
    }
  } else {
    const int o = tid & (OW - 1);
    for (int ko = tid / OW; ko < KOW; ko += 256 / OW) {
      half8 hv, lv;
#pragma unroll
      for (int j = 0; j < 8; ++j) {
        const int k = ko * 8 + j;
        const int kk = (k >= CS) ? 1 : 0;
        const int kc = k - kk * CS;
        int ii;
        if (CS == CIN) ii = kc;
        else ii = (kc == 0) ? 0 : ((kc >= XSPLIT) ? kc - XSPLIT + 1 : -1);
        float w = 0.0f;
        if (ii >= 0) {
          const float* wp = wpool + ((size_t)kk * CIN + ii) * COUT + och + o;
#pragma unroll
          for (int d = 0; d < EMB; ++d)
            w += sE[d] * wp[(size_t)d * (2 * CIN * COUT)];
        }
        _Float16 hh = (_Float16)w;
        hv[j] = hh;
        lv[j] = (_Float16)(w - (float)hh);
      }
      *(half8*)&sWh[((size_t)ko * OW + o) * 8] = hv;
      *(half8*)&sWl[((size_t)ko * OW + o) * 8] = lv;
    }
  }
  if (tid < OW) {
    float bb = 0.0f;
#pragma unroll
    for (int d = 0; d < EMB; ++d) bb += sE[d] * bpool[d * COUT + och + tid];
    sB[tid] = bb;
  }
  __syncthreads();

  // ---- MFMA: A-fragments coalesced half8 from octet-major global ------------
  const size_t bIX = (size_t)n * sIX + (size_t)oIX * 512;
  const size_t bIZ = (size_t)n * sIZ + (size_t)oIZ * 512;
  const size_t bDX = (size_t)n * sDX + (size_t)oDX * 512;
  const size_t bDZ = (size_t)n * sDZ + (size_t)oDZ * 512;
  f32x4 acc[2][NT] = {};
  for (int k0 = 0; k0 < KP; k0 += 32) {
    const int kq = k0 + l4 * 8;
    half8 ah[2], al[2];
#pragma unroll
    for (int mt = 0; mt < 2; ++mt) {
      const int b = wm + mt * 16 + l15;
      if (kq < XSPLIT) {
        const size_t o = bIX + (size_t)(kq >> 3) * 512 + (size_t)b * 8;
        ah[mt] = *(const half8*)&IXh[o];
        al[mt] = *(const half8*)&IXl[o];
      } else if (kq < CS) {
        const size_t o = bIZ + (size_t)((kq - XSPLIT) >> 3) * 512 + (size_t)b * 8;
        ah[mt] = *(const half8*)&IZh[o];
        al[mt] = *(const half8*)&IZl[o];
      } else if (kq < CS + XSPLIT) {
        const size_t o = bDX + (size_t)((kq - CS) >> 3) * 512 + (size_t)b * 8;
        ah[mt] = *(const half8*)&DXh[o];
        al[mt] = *(const half8*)&DXl[o];
      } else if (kq < KD) {
        const size_t o =
            bDZ + (size_t)((kq - CS - XSPLIT) >> 3) * 512 + (size_t)b * 8;
        ah[mt] = *(const half8*)&DZh[o];
        al[mt] = *(const half8*)&DZl[o];
      } else {
        ah[mt] = (half8)(_Float16)0.f;
        al[mt] = (half8)(_Float16)0.f;
      }
    }
    const int koi = kq >> 3;
#pragma unroll
    for (int nt = 0; nt < NT; ++nt) {
      const int ol = wn + nt * 16 + l15;
      half8 bh, bl;
      if constexpr (KP == KD) {
        bh = *(const half8*)&sWh[((size_t)koi * OW + ol) * 8];
        bl = *(const half8*)&sWl[((size_t)koi * OW + ol) * 8];
      } else {
        if (kq < KD) {
          bh = *(const half8*)&sWh[((size_t)koi * OW + ol) * 8];
          bl = *(const half8*)&sWl[((size_t)koi * OW + ol) * 8];
        } else {
          bh = (half8)(_Float16)0.f;
          bl = (half8)(_Float16)0.f;
        }
      }
#pragma unroll
      for (int mt = 0; mt < 2; ++mt) {
        acc[mt][nt] =
            __builtin_amdgcn_mfma_f32_16x16x32_f16(ah[mt], bh, acc[mt][nt], 0, 0, 0);
        acc[mt][nt] =
            __builtin_amdgcn_mfma_f32_16x16x32_f16(ah[mt], bl, acc[mt][nt], 0, 0, 0);
        acc[mt][nt] =
            __builtin_amdgcn_mfma_f32_16x16x32_f16(al[mt], bh, acc[mt][nt], 0, 0, 0);
      }
    }
  }

  // ---- epilogue (octet-major writes) ----
#pragma unroll
  for (int mt = 0; mt < 2; ++mt) {
#pragma unroll
    for (int nt = 0; nt < NT; ++nt) {
      const int ol = wn + nt * 16 + l15;
      const int og = och + ol;  // global output channel
      const float bias = sB[ol];
#pragma unroll
      for (int r = 0; r < 4; ++r) {
        const int b = wm + mt * 16 + l4 * 4 + r;
        const size_t nb = (size_t)n * 64 + b;
        const float v = acc[mt][nt][r] + bias;
        if constexpr (GATE) {
          const float s = 1.0f / (1.0f + expf(-v));
          if (og < 64) {  // z half: write z*h compact (cand GEMM input)
            const float zh = s * hstate[nb * 64 + og];
            const int c2 = cbA + og;
            size_t ia = (size_t)n * 64 * csA + (size_t)(c2 >> 3) * 512 +
                        (size_t)b * 8 + (c2 & 7);
            split_f16(zh, &XAh[ia], &XAl[ia]);
          } else {  // r half
            ZRout[nb * 64 + (og - 64)] = s;
          }
        } else {
          const float hc = tanhf(v);
          const float rr = ZRin[nb * 64 + og];
          const float hold = hstate[nb * 64 + og];
          const float hn = rr * hold + (1.0f - rr) * hc;
          hstate[nb * 64 + og] = hn;
          const int cA = cbA + og;
          size_t ia = (size_t)n * 64 * csA + (size_t)(cA >> 3) * 512 +
                      (size_t)b * 8 + (cA & 7);
          split_f16(hn, &XAh[ia], &XAl[ia]);
        }
      }
    }
  }
}

// ---------------- output head ------------------------------------------------
__global__ __launch_bounds__(256) void head_kernel(const float* __restrict__ h1,
                                                   const float* __restrict__ cw,
                                                   const float* __restrict__ cb,
                                                   float* __restrict__ out) {
  int i = blockIdx.x * 256 + threadIdx.x;
  if (i >= BB * NN) return;
  int n = i % NN, b = i / NN;
  const float* hrow = h1 + ((size_t)n * 64 + b) * 64;
  float hv[64];
#pragma unroll
  for (int j = 0; j < 64; ++j) hv[j] = hrow[j];
  for (int o = 0; o < 12; ++o) {
    float s = cb[o];
#pragma unroll
    for (int j = 0; j < 64; ++j) s += hv[j] * cw[o * 64 + j];
    out[((size_t)b * 12 + o) * NN + n] = s;
  }
}

__global__ __launch_bounds__(256) void zero_f32(float* __restrict__ p, size_t count) {
  size_t i = (size_t)blockIdx.x * 256 + threadIdx.x;
  if (i < count) p[i] = 0.0f;
}
__global__ __launch_bounds__(256) void zero_u16(unsigned short* __restrict__ p,
                                                size_t count) {
  size_t i = (size_t)blockIdx.x * 256 + threadIdx.x;
  if (i < count) p[i] = 0;
}

extern "C" void kernel_launch(void* const* d_in, const int* in_sizes, int n_in,
                              void* d_out, int out_size, void* d_ws, size_t ws_size,
                              hipStream_t stream) {
  const float* src = (const float*)d_in[0];
  const float* E = (const float*)d_in[1];
  const float* w0g = (const float*)d_in[2];
  const float* b0g = (const float*)d_in[3];
  const float* w0c = (const float*)d_in[4];
  const float* b0c = (const float*)d_in[5];
  const float* w1g = (const float*)d_in[6];
  const float* b1g = (const float*)d_in[7];
  const float* w1c = (const float*)d_in[8];
  const float* b1c = (const float*)d_in[9];
  const float* cw = (const float*)d_in[10];
  const float* cb = (const float*)d_in[11];
  float* out = (float*)d_out;
  float* ws = (float*)d_ws;

  size_t off = 0;
  auto alloc = [&](size_t cnt) {  // cnt in floats
    float* p = ws + off;
    off += (cnt + 63) & ~(size_t)63;
    return p;
  };
  const int LS = TT * 512;  // 6144 (12 t-octets)
  const int L1 = 64 * 128;  // 8192 (16 octets)
  const int LZ = 64 * 64;   // 4096 (8 octets)
  _Float16* Ah = (_Float16*)alloc((size_t)KPAD * KPAD / 2);
  _Float16* Al = (_Float16*)alloc((size_t)KPAD * KPAD / 2);
  // contiguous zero span: Xs, Gx, X1a, Xz, Gl1, Gz (hi/lo pairs)
  _Float16* Xsh = (_Float16*)alloc((size_t)KPAD * LS / 2);
  _Float16* Xsl = (_Float16*)alloc((size_t)KPAD * LS / 2);
  _Float16* Gxh = (_Float16*)alloc((size_t)KPAD * LS / 2);
  _Float16* Gxl = (_Float16*)alloc((size_t)KPAD * LS / 2);
  _Float16* X1ah = (_Float16*)alloc((size_t)KPAD * L1 / 2);
  _Float16* X1al = (_Float16*)alloc((size_t)KPAD * L1 / 2);
  _Float16* Xzh = (_Float16*)alloc((size_t)KPAD * LZ / 2);
  _Float16* Xzl = (_Float16*)alloc((size_t)KPAD * LZ / 2);
  _Float16* Gl1h = (_Float16*)alloc((size_t)KPAD * L1 / 2);
  _Float16* Gl1l = (_Float16*)alloc((size_t)KPAD * L1 / 2);
  _Float16* Gzh = (_Float16*)alloc((size_t)KPAD * LZ / 2);
  _Float16* Gzl = (_Float16*)alloc((size_t)KPAD * LZ / 2);
  float* ZR = alloc((size_t)NN * BB * 64);
  float* h0 = alloc((size_t)NN * BB * 64);
  float* h1 = alloc((size_t)NN * BB * 64);
  if (off * sizeof(float) > ws_size) return;  // ws too small: fail loud (zeros)

  // ---- optional precomputed per-node weights (t-invariant) ----
  // sizes in halves per node: gate0 4*18*32*8=18432, cand0 9216,
  // gate1 4*32*32*8=32768, cand1 16384; stored as hi/lo pairs.
  size_t base_off = off;
  _Float16* W0gh = (_Float16*)alloc((size_t)NN * 18432 / 2);
  _Float16* W0gl = (_Float16*)alloc((size_t)NN * 18432 / 2);
  _Float16* W0ch = (_Float16*)alloc((size_t)NN * 9216 / 2);
  _Float16* W0cl = (_Float16*)alloc((size_t)NN * 9216 / 2);
  _Float16* W1gh = (_Float16*)alloc((size_t)NN * 32768 / 2);
  _Float16* W1gl = (_Float16*)alloc((size_t)NN * 32768 / 2);
  _Float16* W1ch = (_Float16*)alloc((size_t)NN * 16384 / 2);
  _Float16* W1cl = (_Float16*)alloc((size_t)NN * 16384 / 2);
  const bool prew = (off * sizeof(float) <= ws_size);
  if (!prew) {
    off = base_off;
    W0gh = W0gl = W0ch = W0cl = W1gh = W1gl = W1ch = W1cl = nullptr;
  }

  adj_kernel<<<NN, 256, 0, stream>>>(E, Ah, Al);
  {
    size_t cx = (size_t)2 * KPAD * (LS + LS + L1 + LZ + L1 + LZ);  // halves
    size_t chh = (size_t)2 * NN * BB * 64;  // floats (h0,h1 contiguous)
    zero_u16<<<(int)((cx + 255) / 256), 256, 0, stream>>>((unsigned short*)Xsh, cx);
    zero_f32<<<(int)((chh + 255) / 256), 256, 0, stream>>>(h0, chh);
  }
  // Pre-loop: Gx = A @ Xs  (all 12 steps' x diffused, once)
  srcall_kernel<<<(NN * BB * TT + 255) / 256, 256, 0, stream>>>(src, Xsh, Xsl);
  mfma_gemm3<<<dim3(LS / 128, 7), 256, 0, stream>>>(Ah, Al, Xsh, Xsl, Gxh, Gxl, LS);
  // One-time W precompute (removes per-step W-gen L2 storm from gconvs)
  if (prew) {
    wgen_pre<72, 65, 8, 32, 128><<<NN * 4, 256, 0, stream>>>(E, w0g, W0gh, W0gl);
    wgen_pre<72, 65, 8, 32, 64><<<NN * 2, 256, 0, stream>>>(E, w0c, W0ch, W0cl);
    wgen_pre<128, 128, 64, 32, 128><<<NN * 4, 256, 0, stream>>>(E, w1g, W1gh, W1gl);
    wgen_pre<128, 128, 64, 32, 64><<<NN * 2, 256, 0, stream>>>(E, w1c, W1ch, W1cl);
  }

  const int gx1 = L1 / 128;  // 64
  const int gxz = LZ / 128;  // 32
  const int NQ8 = ((NN + 7) / 8) * 8;  // 888
  const int g_gate = NQ8 * 4;          // C=4 chunks (OW=32, COUT=128)
  const int g_cand = NQ8 * 2;          // C=2 chunks (OW=32, COUT=64)
  for (int t = 0; t < TT; ++t) {
    // ---- layer 0: identity x <- Xs[t], h0 <- X1a octets 0-7;
    //      diffused x <- Gx[t], diffused h0 <- Gl1 octets 0-7 (step t-1) ----
    gconv_fused<72, 65, 8, 32, true><<<g_gate, 256, 0, stream>>>(
        Xsh, Xsl, LS, t, X1ah, X1al, L1, 0, Gxh, Gxl, LS, t, Gl1h, Gl1l, L1, 0,
        E, w0g, b0g, nullptr, h0, ZR, Xzh, Xzl, 64, 0, W0gh, W0gl);
    mfma_gemm3<<<dim3(gxz, 7), 256, 0, stream>>>(Ah, Al, Xzh, Xzl, Gzh, Gzl, LZ);
    gconv_fused<72, 65, 8, 32, false><<<g_cand, 256, 0, stream>>>(
        Xsh, Xsl, LS, t, Xzh, Xzl, LZ, 0, Gxh, Gxl, LS, t, Gzh, Gzl, LZ, 0,
        E, w0c, b0c, ZR, h0, nullptr, X1ah, X1al, 128, 0, W0ch, W0cl);
    // ---- layer 1: identity h0 <- X1a oct 0-7, h1 <- X1a oct 8-15 ----
    mfma_gemm3<<<dim3(gx1, 7), 256, 0, stream>>>(Ah, Al, X1ah, X1al, Gl1h, Gl1l, L1);
    gconv_fused<128, 128, 64, 32, true><<<g_gate, 256, 0, stream>>>(
        X1ah, X1al, L1, 0, X1ah, X1al, L1, 8, Gl1h, Gl1l, L1, 0, Gl1h, Gl1l, L1, 8,
        E, w1g, b1g, nullptr, h1, ZR, Xzh, Xzl, 64, 0, W1gh, W1gl);
    mfma_gemm3<<<dim3(gxz, 7), 256, 0, stream>>>(Ah, Al, Xzh, Xzl, Gzh, Gzl, LZ);
    gconv_fused<128, 128, 64, 32, false><<<g_cand, 256, 0, stream>>>(
        X1ah, X1al, L1, 0, Xzh, Xzl, LZ, 0, Gl1h, Gl1l, L1, 0, Gzh, Gzl, LZ, 0,
        E, w1c, b1c, ZR, h1, nullptr, X1ah, X1al, 128, 64, W1ch, W1cl);
  }
  head_kernel<<<(BB * NN + 255) / 256, 256, 0, stream>>>(h1, cw, cb, out);
}

// Round 2
// 3837.182 us; speedup vs baseline: 1.0432x; 1.0432x over previous
//
#include <hip/hip_runtime.h>
#include <cstddef>

#define NN 883
#define BB 64
#define TT 12
#define EMB 10
#define KPAD 896  // node dim padded to multiple of 128

typedef short short8 __attribute__((ext_vector_type(8)));
typedef _Float16 half8 __attribute__((ext_vector_type(8)));
typedef float f32x4 __attribute__((ext_vector_type(4)));

__device__ __forceinline__ void split_f16(float v, _Float16* hp, _Float16* lp) {
  _Float16 h = (_Float16)v;
  *hp = h;
  *lp = (_Float16)(v - (float)h);
}

// -------- adjacency: A = softmax(relu(E E^T), axis=1), emitted as f16 hi/lo --
__global__ __launch_bounds__(256) void adj_kernel(const float* __restrict__ E,
                                                  _Float16* __restrict__ Ah,
                                                  _Float16* __restrict__ Al) {
  const int n = blockIdx.x;
  const int tid = threadIdx.x;
  __shared__ float sE[EMB];
  __shared__ float sred[256];
  if (tid < EMB) sE[tid] = E[n * EMB + tid];
  __syncthreads();
  float d[4];
  float lmax = 0.0f;
#pragma unroll
  for (int q = 0; q < 4; ++q) {
    int m = tid + q * 256;
    d[q] = 0.0f;
    if (m < NN) {
      float s = 0.0f;
#pragma unroll
      for (int e = 0; e < EMB; ++e) s += sE[e] * E[m * EMB + e];
      d[q] = fmaxf(s, 0.0f);
      lmax = fmaxf(lmax, d[q]);
    }
  }
  sred[tid] = lmax;
  __syncthreads();
  for (int s = 128; s > 0; s >>= 1) {
    if (tid < s) sred[tid] = fmaxf(sred[tid], sred[tid + s]);
    __syncthreads();
  }
  const float mx = sred[0];
  __syncthreads();
  float lsum = 0.0f;
#pragma unroll
  for (int q = 0; q < 4; ++q) {
    int m = tid + q * 256;
    if (m < NN) {
      d[q] = expf(d[q] - mx);
      lsum += d[q];
    }
  }
  sred[tid] = lsum;
  __syncthreads();
  for (int s = 128; s > 0; s >>= 1) {
    if (tid < s) sred[tid] += sred[tid + s];
    __syncthreads();
  }
  const float inv = 1.0f / sred[0];
#pragma unroll
  for (int q = 0; q < 4; ++q) {
    int m = tid + q * 256;
    if (m < KPAD) {
      float v = (m < NN) ? d[q] * inv : 0.0f;
      split_f16(v, &Ah[(size_t)n * KPAD + m], &Al[(size_t)n * KPAD + m]);
    }
  }
}

// -------- 3-term split-f16 MFMA GEMM; output written as split f16 ------------
__global__ __launch_bounds__(256) void mfma_gemm3(const _Float16* __restrict__ Ah,
                                                  const _Float16* __restrict__ Al,
                                                  const _Float16* __restrict__ Xh,
                                                  const _Float16* __restrict__ Xl,
                                                  _Float16* __restrict__ Gh,
                                                  _Float16* __restrict__ Gl, int L) {
  __shared__ _Float16 sA[2][128][40];
  __shared__ _Float16 sX[2][4][128][8];
  const int tid = threadIdx.x;
  const int lane = tid & 63;
  const int wid = tid >> 6;
  const int wm = (wid >> 1) * 64, wn = (wid & 1) * 64;
  const int bm = blockIdx.y * 128;
  const int bl = blockIdx.x * 128;
  const int l15 = lane & 15, l4 = lane >> 4;

  f32x4 acc[4][4] = {};

  const int xlp = (tid & 63) * 2;
  const int xko = tid >> 6;

  for (int k0 = 0; k0 < KPAD; k0 += 32) {
    __syncthreads();
#pragma unroll
    for (int p = 0; p < 2; ++p) {
      int i = tid + p * 256;
      int m = i >> 2, k8 = (i & 3) * 8;
      *(half8*)&sA[0][m][k8] = *(const half8*)&Ah[(size_t)(bm + m) * KPAD + k0 + k8];
      *(half8*)&sA[1][m][k8] = *(const half8*)&Al[(size_t)(bm + m) * KPAD + k0 + k8];
    }
    {
      int gl = bl + xlp;
      int kb = k0 + xko * 8;
#pragma unroll
      for (int buf = 0; buf < 2; ++buf) {
        const _Float16* Xp = buf ? Xl : Xh;
        unsigned int v[8];
#pragma unroll
        for (int j = 0; j < 8; ++j)
          v[j] = *(const unsigned int*)&Xp[(size_t)(kb + j) * L + gl];
        short8 lo, hi;
#pragma unroll
        for (int j = 0; j < 8; ++j) {
          lo[j] = (short)(v[j] & 0xFFFFu);
          hi[j] = (short)(v[j] >> 16);
        }
        *(short8*)&sX[buf][xko][xlp][0] = lo;
        *(short8*)&sX[buf][xko][xlp + 1][0] = hi;
      }
    }
    __syncthreads();
    half8 afh[4], afl[4], bfh[4], bfl[4];
#pragma unroll
    for (int mi = 0; mi < 4; ++mi) {
      afh[mi] = *(half8*)&sA[0][wm + mi * 16 + l15][l4 * 8];
      afl[mi] = *(half8*)&sA[1][wm + mi * 16 + l15][l4 * 8];
    }
#pragma unroll
    for (int ni = 0; ni < 4; ++ni) {
      bfh[ni] = *(half8*)&sX[0][l4][wn + ni * 16 + l15][0];
      bfl[ni] = *(half8*)&sX[1][l4][wn + ni * 16 + l15][0];
    }
#pragma unroll
    for (int mi = 0; mi < 4; ++mi)
#pragma unroll
      for (int ni = 0; ni < 4; ++ni) {
        acc[mi][ni] = __builtin_amdgcn_mfma_f32_16x16x32_f16(afh[mi], bfh[ni],
                                                             acc[mi][ni], 0, 0, 0);
        acc[mi][ni] = __builtin_amdgcn_mfma_f32_16x16x32_f16(afh[mi], bfl[ni],
                                                             acc[mi][ni], 0, 0, 0);
        acc[mi][ni] = __builtin_amdgcn_mfma_f32_16x16x32_f16(afl[mi], bfh[ni],
                                                             acc[mi][ni], 0, 0, 0);
      }
  }
#pragma unroll
  for (int mi = 0; mi < 4; ++mi) {
    int row0 = bm + wm + mi * 16 + l4 * 4;
#pragma unroll
    for (int ni = 0; ni < 4; ++ni) {
      int col = bl + wn + ni * 16 + l15;
#pragma unroll
      for (int r = 0; r < 4; ++r) {
        int row = row0 + r;
        if (row < NN)
          split_f16(acc[mi][ni][r], &Gh[(size_t)row * L + col],
                    &Gl[(size_t)row * L + col]);
      }
    }
  }
}

// -------- build Xs: all 12 steps' x, octet-major [n][t][b][8] (j=0 only) -----
__global__ __launch_bounds__(256) void srcall_kernel(const float* __restrict__ src,
                                                     _Float16* __restrict__ Xsh,
                                                     _Float16* __restrict__ Xsl) {
  int i = blockIdx.x * 256 + threadIdx.x;
  if (i >= NN * BB * TT) return;
  int t = i % TT;
  int nb = i / TT;
  int b = nb & 63, n = nb >> 6;
  float v = src[((size_t)b * TT + t) * NN + n];
  size_t idx = (size_t)n * (TT * 512) + (size_t)t * 512 + (size_t)b * 8;
  split_f16(v, &Xsh[idx], &Xsl[idx]);
}

// -------- one-time per-node weight gen (t-invariant!) ------------------------
// Writes split-f16 weights in exactly the gconv LDS tile layout:
// per (node n, o-chunk oc): [KOW][OW][8] halves, flat 16B-aligned.
template <int CS, int CIN, int XSPLIT, int OW, int COUT>
__global__ __launch_bounds__(256) void wgen_pre(const float* __restrict__ E,
                                                const float* __restrict__ wpool,
                                                _Float16* __restrict__ Wh,
                                                _Float16* __restrict__ Wl) {
  constexpr int C = COUT / OW;
  constexpr int KD = 2 * CS;
  constexpr int KOW = KD / 8;
  const int bid = blockIdx.x;
  const int n = bid / C;
  const int oc = bid % C;
  if (n >= NN) return;
  const int och = oc * OW;
  const int tid = threadIdx.x;
  __shared__ float sE[EMB];
  if (tid < EMB) sE[tid] = E[n * EMB + tid];
  __syncthreads();
  _Float16* bh = Wh + ((size_t)n * C + oc) * ((size_t)KOW * OW * 8);
  _Float16* bl = Wl + ((size_t)n * C + oc) * ((size_t)KOW * OW * 8);
  const int o = tid & (OW - 1);
  for (int ko = tid / OW; ko < KOW; ko += 256 / OW) {
    half8 hv, lv;
#pragma unroll
    for (int j = 0; j < 8; ++j) {
      const int k = ko * 8 + j;
      const int kk = (k >= CS) ? 1 : 0;
      const int kc = k - kk * CS;
      int ii;
      if (CS == CIN) ii = kc;
      else ii = (kc == 0) ? 0 : ((kc >= XSPLIT) ? kc - XSPLIT + 1 : -1);
      float w = 0.0f;
      if (ii >= 0) {
        const float* wp = wpool + ((size_t)kk * CIN + ii) * COUT + och + o;
#pragma unroll
        for (int d = 0; d < EMB; ++d)
          w += sE[d] * wp[(size_t)d * (2 * CIN * COUT)];
      }
      _Float16 hh = (_Float16)w;
      hv[j] = hh;
      lv[j] = (_Float16)(w - (float)hh);
    }
    *(half8*)&bh[((size_t)ko * OW + o) * 8] = hv;
    *(half8*)&bl[((size_t)ko * OW + o) * 8] = lv;
  }
}

// -------- fused per-node gconv: W from precompute (or fused gen) + MFMA ------
// All operand buffers octet-major per node: [n][ko][b][8], channel = ko*8+j.
// K regions: [0,XSPLIT) IX; [XSPLIT,CS) IZ; [CS,CS+XSPLIT) DX; [CS+XSPLIT,KD) DZ.
// OW: o-tile width per block; C = COUT/OW o-chunks per node.
// 1D grid with XCD swizzle: id = (n%8) + 8*(C*(n/8) + oc) puts all C chunks
// of node n on the SAME XCD so the node's X/G rows are fetched once per L2.
// GATE: o_global<64 -> z-half writes z*h into XA (=Xz); else r -> ZRout.
// !GATE: GRU update, writes h-state + split-f16 h into XA.
// PWh/PWl: precomputed split-f16 weights (wgen_pre layout); nullptr -> fused gen.
template <int CS, int CIN, int XSPLIT, int OW, bool GATE>
__global__ __launch_bounds__(256) void gconv_fused(
    const _Float16* __restrict__ IXh, const _Float16* __restrict__ IXl, int sIX, int oIX,
    const _Float16* __restrict__ IZh, const _Float16* __restrict__ IZl, int sIZ, int oIZ,
    const _Float16* __restrict__ DXh, const _Float16* __restrict__ DXl, int sDX, int oDX,
    const _Float16* __restrict__ DZh, const _Float16* __restrict__ DZl, int sDZ, int oDZ,
    const float* __restrict__ E, const float* __restrict__ wpool,
    const float* __restrict__ bpool, const float* __restrict__ ZRin,
    float* __restrict__ hstate, float* __restrict__ ZRout,
    _Float16* __restrict__ XAh, _Float16* __restrict__ XAl, int csA, int cbA,
    const _Float16* __restrict__ PWh, const _Float16* __restrict__ PWl) {
  constexpr int COUT = GATE ? 128 : 64;
  constexpr int C = COUT / OW;         // o-chunks per node
  constexpr int KD = 2 * CS;
  constexpr int KP = (KD + 31) & ~31;  // 160 / 256 (MFMA loop extent)
  constexpr int KOW = KD / 8;          // 18 / 32 (W octets actually stored)
  constexpr int NT = OW / 32;          // n-tiles per wave
  // XCD swizzle decode
  const int bid = blockIdx.x;
  const int xcd = bid & 7;
  const int rest = bid >> 3;
  const int oc = rest % C;
  const int nq = rest / C;
  const int n = nq * 8 + xcd;
  if (n >= NN) return;
  const int och = oc * OW;
  const int tid = threadIdx.x;
  const int lane = tid & 63, wid = tid >> 6;
  const int wm = (wid & 1) * 32;
  const int wn = (wid >> 1) * (OW / 2);
  const int l15 = lane & 15, l4 = lane >> 4;

  __shared__ float sE[EMB];
  __shared__ float sB[OW];
  __shared__ _Float16 sWh[KOW * OW * 8];
  __shared__ _Float16 sWl[KOW * OW * 8];

  if (tid < EMB) sE[tid] = E[n * EMB + tid];
  __syncthreads();

  // ---- W: stream precomputed tile, or fused gen fallback --------------------
  if (PWh != nullptr) {
    const size_t wbase = ((size_t)n * C + oc) * ((size_t)KOW * OW * 8);
    for (int i = tid; i < KOW * OW; i += 256) {
      *(half8*)&sWh[(size_t)i * 8] = *(const half8*)&PWh[wbase + (size_t)i * 8];
      *(half8*)&sWl[(size_t)i * 8] = *(const half8*)&PWl[wbase + (size_t)i * 8];
    }
  } else {
    const int o = tid & (OW - 1);
    for (int ko = tid / OW; ko < KOW; ko += 256 / OW) {
      half8 hv, lv;
#pragma unroll
      for (int j = 0; j < 8; ++j) {
        const int k = ko * 8 + j;
        const int kk = (k >= CS) ? 1 : 0;
        const int kc = k - kk * CS;
        int ii;
        if (CS == CIN) ii = kc;
        else ii = (kc == 0) ? 0 : ((kc >= XSPLIT) ? kc - XSPLIT + 1 : -1);
        float w = 0.0f;
        if (ii >= 0) {
          const float* wp = wpool + ((size_t)kk * CIN + ii) * COUT + och + o;
#pragma unroll
          for (int d = 0; d < EMB; ++d)
            w += sE[d] * wp[(size_t)d * (2 * CIN * COUT)];
        }
        _Float16 hh = (_Float16)w;
        hv[j] = hh;
        lv[j] = (_Float16)(w - (float)hh);
      }
      *(half8*)&sWh[((size_t)ko * OW + o) * 8] = hv;
      *(half8*)&sWl[((size_t)ko * OW + o) * 8] = lv;
    }
  }
  if (tid < OW) {
    float bb = 0.0f;
#pragma unroll
    for (int d = 0; d < EMB; ++d) bb += sE[d] * bpool[d * COUT + och + tid];
    sB[tid] = bb;
  }
  __syncthreads();

  // ---- MFMA: A-fragments coalesced half8 from octet-major global ------------
  const size_t bIX = (size_t)n * sIX + (size_t)oIX * 512;
  const size_t bIZ = (size_t)n * sIZ + (size_t)oIZ * 512;
  const size_t bDX = (size_t)n * sDX + (size_t)oDX * 512;
  const size_t bDZ = (size_t)n * sDZ + (size_t)oDZ * 512;
  f32x4 acc[2][NT] = {};
  for (int k0 = 0; k0 < KP; k0 += 32) {
    const int kq = k0 + l4 * 8;
    half8 ah[2], al[2];
#pragma unroll
    for (int mt = 0; mt < 2; ++mt) {
      const int b = wm + mt * 16 + l15;
      if (kq < XSPLIT) {
        const size_t o = bIX + (size_t)(kq >> 3) * 512 + (size_t)b * 8;
        ah[mt] = *(const half8*)&IXh[o];
        al[mt] = *(const half8*)&IXl[o];
      } else if (kq < CS) {
        const size_t o = bIZ + (size_t)((kq - XSPLIT) >> 3) * 512 + (size_t)b * 8;
        ah[mt] = *(const half8*)&IZh[o];
        al[mt] = *(const half8*)&IZl[o];
      } else if (kq < CS + XSPLIT) {
        const size_t o = bDX + (size_t)((kq - CS) >> 3) * 512 + (size_t)b * 8;
        ah[mt] = *(const half8*)&DXh[o];
        al[mt] = *(const half8*)&DXl[o];
      } else if (kq < KD) {
        const size_t o =
            bDZ + (size_t)((kq - CS - XSPLIT) >> 3) * 512 + (size_t)b * 8;
        ah[mt] = *(const half8*)&DZh[o];
        al[mt] = *(const half8*)&DZl[o];
      } else {
        ah[mt] = (half8)(_Float16)0.f;
        al[mt] = (half8)(_Float16)0.f;
      }
    }
    const int koi = kq >> 3;
#pragma unroll
    for (int nt = 0; nt < NT; ++nt) {
      const int ol = wn + nt * 16 + l15;
      half8 bh, bl;
      if constexpr (KP == KD) {
        bh = *(const half8*)&sWh[((size_t)koi * OW + ol) * 8];
        bl = *(const half8*)&sWl[((size_t)koi * OW + ol) * 8];
      } else {
        if (kq < KD) {
          bh = *(const half8*)&sWh[((size_t)koi * OW + ol) * 8];
          bl = *(const half8*)&sWl[((size_t)koi * OW + ol) * 8];
        } else {
          bh = (half8)(_Float16)0.f;
          bl = (half8)(_Float16)0.f;
        }
      }
#pragma unroll
      for (int mt = 0; mt < 2; ++mt) {
        acc[mt][nt] =
            __builtin_amdgcn_mfma_f32_16x16x32_f16(ah[mt], bh, acc[mt][nt], 0, 0, 0);
        acc[mt][nt] =
            __builtin_amdgcn_mfma_f32_16x16x32_f16(ah[mt], bl, acc[mt][nt], 0, 0, 0);
        acc[mt][nt] =
            __builtin_amdgcn_mfma_f32_16x16x32_f16(al[mt], bh, acc[mt][nt], 0, 0, 0);
      }
    }
  }

  // ---- epilogue (octet-major writes) ----
#pragma unroll
  for (int mt = 0; mt < 2; ++mt) {
#pragma unroll
    for (int nt = 0; nt < NT; ++nt) {
      const int ol = wn + nt * 16 + l15;
      const int og = och + ol;  // global output channel
      const float bias = sB[ol];
#pragma unroll
      for (int r = 0; r < 4; ++r) {
        const int b = wm + mt * 16 + l4 * 4 + r;
        const size_t nb = (size_t)n * 64 + b;
        const float v = acc[mt][nt][r] + bias;
        if constexpr (GATE) {
          const float s = 1.0f / (1.0f + expf(-v));
          if (og < 64) {  // z half: write z*h compact (cand GEMM input)
            const float zh = s * hstate[nb * 64 + og];
            const int c2 = cbA + og;
            size_t ia = (size_t)n * 64 * csA + (size_t)(c2 >> 3) * 512 +
                        (size_t)b * 8 + (c2 & 7);
            split_f16(zh, &XAh[ia], &XAl[ia]);
          } else {  // r half
            ZRout[nb * 64 + (og - 64)] = s;
          }
        } else {
          const float hc = tanhf(v);
          const float rr = ZRin[nb * 64 + og];
          const float hold = hstate[nb * 64 + og];
          const float hn = rr * hold + (1.0f - rr) * hc;
          hstate[nb * 64 + og] = hn;
          const int cA = cbA + og;
          size_t ia = (size_t)n * 64 * csA + (size_t)(cA >> 3) * 512 +
                      (size_t)b * 8 + (cA & 7);
          split_f16(hn, &XAh[ia], &XAl[ia]);
        }
      }
    }
  }
}

// ---------------- output head ------------------------------------------------
__global__ __launch_bounds__(256) void head_kernel(const float* __restrict__ h1,
                                                   const float* __restrict__ cw,
                                                   const float* __restrict__ cb,
                                                   float* __restrict__ out) {
  int i = blockIdx.x * 256 + threadIdx.x;
  if (i >= BB * NN) return;
  int n = i % NN, b = i / NN;
  const float* hrow = h1 + ((size_t)n * 64 + b) * 64;
  float hv[64];
#pragma unroll
  for (int j = 0; j < 64; ++j) hv[j] = hrow[j];
  for (int o = 0; o < 12; ++o) {
    float s = cb[o];
#pragma unroll
    for (int j = 0; j < 64; ++j) s += hv[j] * cw[o * 64 + j];
    out[((size_t)b * 12 + o) * NN + n] = s;
  }
}

__global__ __launch_bounds__(256) void zero_f32(float* __restrict__ p, size_t count) {
  size_t i = (size_t)blockIdx.x * 256 + threadIdx.x;
  if (i < count) p[i] = 0.0f;
}
__global__ __launch_bounds__(256) void zero_u16(unsigned short* __restrict__ p,
                                                size_t count) {
  size_t i = (size_t)blockIdx.x * 256 + threadIdx.x;
  if (i < count) p[i] = 0;
}

extern "C" void kernel_launch(void* const* d_in, const int* in_sizes, int n_in,
                              void* d_out, int out_size, void* d_ws, size_t ws_size,
                              hipStream_t stream) {
  const float* src = (const float*)d_in[0];
  const float* E = (const float*)d_in[1];
  const float* w0g = (const float*)d_in[2];
  const float* b0g = (const float*)d_in[3];
  const float* w0c = (const float*)d_in[4];
  const float* b0c = (const float*)d_in[5];
  const float* w1g = (const float*)d_in[6];
  const float* b1g = (const float*)d_in[7];
  const float* w1c = (const float*)d_in[8];
  const float* b1c = (const float*)d_in[9];
  const float* cw = (const float*)d_in[10];
  const float* cb = (const float*)d_in[11];
  float* out = (float*)d_out;
  float* ws = (float*)d_ws;

  size_t off = 0;
  auto alloc = [&](size_t cnt) {  // cnt in floats
    float* p = ws + off;
    off += (cnt + 63) & ~(size_t)63;
    return p;
  };
  const int LS = TT * 512;  // 6144 (12 t-octets)
  const int L1 = 64 * 128;  // 8192 (16 octets)
  const int LZ = 64 * 64;   // 4096 (8 octets)
  _Float16* Ah = (_Float16*)alloc((size_t)KPAD * KPAD / 2);
  _Float16* Al = (_Float16*)alloc((size_t)KPAD * KPAD / 2);
  // contiguous zero span: Xs, Gx, X1a, Xz, Gl1, Gz (hi/lo pairs)
  _Float16* Xsh = (_Float16*)alloc((size_t)KPAD * LS / 2);
  _Float16* Xsl = (_Float16*)alloc((size_t)KPAD * LS / 2);
  _Float16* Gxh = (_Float16*)alloc((size_t)KPAD * LS / 2);
  _Float16* Gxl = (_Float16*)alloc((size_t)KPAD * LS / 2);
  _Float16* X1ah = (_Float16*)alloc((size_t)KPAD * L1 / 2);
  _Float16* X1al = (_Float16*)alloc((size_t)KPAD * L1 / 2);
  _Float16* Xzh = (_Float16*)alloc((size_t)KPAD * LZ / 2);
  _Float16* Xzl = (_Float16*)alloc((size_t)KPAD * LZ / 2);
  _Float16* Gl1h = (_Float16*)alloc((size_t)KPAD * L1 / 2);
  _Float16* Gl1l = (_Float16*)alloc((size_t)KPAD * L1 / 2);
  _Float16* Gzh = (_Float16*)alloc((size_t)KPAD * LZ / 2);
  _Float16* Gzl = (_Float16*)alloc((size_t)KPAD * LZ / 2);
  float* ZR = alloc((size_t)NN * BB * 64);
  float* h0 = alloc((size_t)NN * BB * 64);
  float* h1 = alloc((size_t)NN * BB * 64);
  if (off * sizeof(float) > ws_size) return;  // ws too small: fail loud (zeros)

  // ---- tiered precomputed per-node weights (t-invariant) ----
  // Flavor f: halves per node (hi or lo each): g0 18432, c0 9216, g1 32768,
  // c1 16384. Each flavor costs `halves` FLOATS of ws (hi+lo combined).
  // Enumerate all 16 subsets, pick max total bytes that fits -> graceful
  // degradation for unknown ws_size (r1 post-mortem: all-or-nothing never fit).
  const size_t wsfl = ws_size / sizeof(float);
  const size_t whalves[4] = {(size_t)NN * 18432, (size_t)NN * 9216,
                             (size_t)NN * 32768, (size_t)NN * 16384};
  const size_t avail = (wsfl > off) ? (wsfl - off) : 0;
  int best = 0;
  size_t bestsz = 0;
  for (int s = 1; s < 16; ++s) {
    size_t tot = 0;
    for (int f = 0; f < 4; ++f)
      if (s & (1 << f)) tot += whalves[f] + 128;  // +alignment slack
    if (tot <= avail && tot > bestsz) {
      bestsz = tot;
      best = s;
    }
  }
  _Float16 *W0gh = nullptr, *W0gl = nullptr, *W0ch = nullptr, *W0cl = nullptr;
  _Float16 *W1gh = nullptr, *W1gl = nullptr, *W1ch = nullptr, *W1cl = nullptr;
  if (best & 1) {
    W0gh = (_Float16*)alloc(whalves[0] / 2);
    W0gl = (_Float16*)alloc(whalves[0] / 2);
  }
  if (best & 2) {
    W0ch = (_Float16*)alloc(whalves[1] / 2);
    W0cl = (_Float16*)alloc(whalves[1] / 2);
  }
  if (best & 4) {
    W1gh = (_Float16*)alloc(whalves[2] / 2);
    W1gl = (_Float16*)alloc(whalves[2] / 2);
  }
  if (best & 8) {
    W1ch = (_Float16*)alloc(whalves[3] / 2);
    W1cl = (_Float16*)alloc(whalves[3] / 2);
  }

  adj_kernel<<<NN, 256, 0, stream>>>(E, Ah, Al);
  {
    size_t cx = (size_t)2 * KPAD * (LS + LS + L1 + LZ + L1 + LZ);  // halves
    size_t chh = (size_t)2 * NN * BB * 64;  // floats (h0,h1 contiguous)
    zero_u16<<<(int)((cx + 255) / 256), 256, 0, stream>>>((unsigned short*)Xsh, cx);
    zero_f32<<<(int)((chh + 255) / 256), 256, 0, stream>>>(h0, chh);
  }
  // Pre-loop: Gx = A @ Xs  (all 12 steps' x diffused, once)
  srcall_kernel<<<(NN * BB * TT + 255) / 256, 256, 0, stream>>>(src, Xsh, Xsl);
  mfma_gemm3<<<dim3(LS / 128, 7), 256, 0, stream>>>(Ah, Al, Xsh, Xsl, Gxh, Gxl, LS);
  // One-time W precompute for fitted flavors (kills per-step W-gen L2 storm)
  if (W0gh) wgen_pre<72, 65, 8, 32, 128><<<NN * 4, 256, 0, stream>>>(E, w0g, W0gh, W0gl);
  if (W0ch) wgen_pre<72, 65, 8, 32, 64><<<NN * 2, 256, 0, stream>>>(E, w0c, W0ch, W0cl);
  if (W1gh) wgen_pre<128, 128, 64, 32, 128><<<NN * 4, 256, 0, stream>>>(E, w1g, W1gh, W1gl);
  if (W1ch) wgen_pre<128, 128, 64, 32, 64><<<NN * 2, 256, 0, stream>>>(E, w1c, W1ch, W1cl);

  const int gx1 = L1 / 128;  // 64
  const int gxz = LZ / 128;  // 32
  const int NQ8 = ((NN + 7) / 8) * 8;  // 888
  const int g_gate = NQ8 * 4;          // C=4 chunks (OW=32, COUT=128)
  const int g_cand = NQ8 * 2;          // C=2 chunks (OW=32, COUT=64)
  for (int t = 0; t < TT; ++t) {
    // ---- layer 0: identity x <- Xs[t], h0 <- X1a octets 0-7;
    //      diffused x <- Gx[t], diffused h0 <- Gl1 octets 0-7 (step t-1) ----
    gconv_fused<72, 65, 8, 32, true><<<g_gate, 256, 0, stream>>>(
        Xsh, Xsl, LS, t, X1ah, X1al, L1, 0, Gxh, Gxl, LS, t, Gl1h, Gl1l, L1, 0,
        E, w0g, b0g, nullptr, h0, ZR, Xzh, Xzl, 64, 0, W0gh, W0gl);
    mfma_gemm3<<<dim3(gxz, 7), 256, 0, stream>>>(Ah, Al, Xzh, Xzl, Gzh, Gzl, LZ);
    gconv_fused<72, 65, 8, 32, false><<<g_cand, 256, 0, stream>>>(
        Xsh, Xsl, LS, t, Xzh, Xzl, LZ, 0, Gxh, Gxl, LS, t, Gzh, Gzl, LZ, 0,
        E, w0c, b0c, ZR, h0, nullptr, X1ah, X1al, 128, 0, W0ch, W0cl);
    // ---- layer 1: identity h0 <- X1a oct 0-7, h1 <- X1a oct 8-15 ----
    mfma_gemm3<<<dim3(gx1, 7), 256, 0, stream>>>(Ah, Al, X1ah, X1al, Gl1h, Gl1l, L1);
    gconv_fused<128, 128, 64, 32, true><<<g_gate, 256, 0, stream>>>(
        X1ah, X1al, L1, 0, X1ah, X1al, L1, 8, Gl1h, Gl1l, L1, 0, Gl1h, Gl1l, L1, 8,
        E, w1g, b1g, nullptr, h1, ZR, Xzh, Xzl, 64, 0, W1gh, W1gl);
    mfma_gemm3<<<dim3(gxz, 7), 256, 0, stream>>>(Ah, Al, Xzh, Xzl, Gzh, Gzl, LZ);
    gconv_fused<128, 128, 64, 32, false><<<g_cand, 256, 0, stream>>>(
        X1ah, X1al, L1, 0, Xzh, Xzl, LZ, 0, Gl1h, Gl1l, L1, 0, Gzh, Gzl, LZ, 0,
        E, w1c, b1c, ZR, h1, nullptr, X1ah, X1al, 128, 64, W1ch, W1cl);
  }
  head_kernel<<<(BB * NN + 255) / 256, 256, 0, stream>>>(h1, cw, cb, out);
}

// Round 3
// 3782.051 us; speedup vs baseline: 1.0584x; 1.0146x over previous
//
#include <hip/hip_runtime.h>
#include <cstddef>

#define NN 883
#define BB 64
#define TT 12
#define EMB 10
#define KPAD 896  // node dim padded to multiple of 128

typedef short short8 __attribute__((ext_vector_type(8)));
typedef _Float16 half8 __attribute__((ext_vector_type(8)));
typedef float f32x4 __attribute__((ext_vector_type(4)));

__device__ __forceinline__ void split_f16(float v, _Float16* hp, _Float16* lp) {
  _Float16 h = (_Float16)v;
  *hp = h;
  *lp = (_Float16)(v - (float)h);
}

// -------- adjacency: A = softmax(relu(E E^T), axis=1), emitted as f16 hi/lo --
__global__ __launch_bounds__(256) void adj_kernel(const float* __restrict__ E,
                                                  _Float16* __restrict__ Ah,
                                                  _Float16* __restrict__ Al) {
  const int n = blockIdx.x;
  const int tid = threadIdx.x;
  __shared__ float sE[EMB];
  __shared__ float sred[256];
  if (tid < EMB) sE[tid] = E[n * EMB + tid];
  __syncthreads();
  float d[4];
  float lmax = 0.0f;
#pragma unroll
  for (int q = 0; q < 4; ++q) {
    int m = tid + q * 256;
    d[q] = 0.0f;
    if (m < NN) {
      float s = 0.0f;
#pragma unroll
      for (int e = 0; e < EMB; ++e) s += sE[e] * E[m * EMB + e];
      d[q] = fmaxf(s, 0.0f);
      lmax = fmaxf(lmax, d[q]);
    }
  }
  sred[tid] = lmax;
  __syncthreads();
  for (int s = 128; s > 0; s >>= 1) {
    if (tid < s) sred[tid] = fmaxf(sred[tid], sred[tid + s]);
    __syncthreads();
  }
  const float mx = sred[0];
  __syncthreads();
  float lsum = 0.0f;
#pragma unroll
  for (int q = 0; q < 4; ++q) {
    int m = tid + q * 256;
    if (m < NN) {
      d[q] = expf(d[q] - mx);
      lsum += d[q];
    }
  }
  sred[tid] = lsum;
  __syncthreads();
  for (int s = 128; s > 0; s >>= 1) {
    if (tid < s) sred[tid] += sred[tid + s];
    __syncthreads();
  }
  const float inv = 1.0f / sred[0];
#pragma unroll
  for (int q = 0; q < 4; ++q) {
    int m = tid + q * 256;
    if (m < KPAD) {
      float v = (m < NN) ? d[q] * inv : 0.0f;
      split_f16(v, &Ah[(size_t)n * KPAD + m], &Al[(size_t)n * KPAD + m]);
    }
  }
}

// -------- 3-term split-f16 MFMA GEMM; output written as split f16 ------------
__global__ __launch_bounds__(256) void mfma_gemm3(const _Float16* __restrict__ Ah,
                                                  const _Float16* __restrict__ Al,
                                                  const _Float16* __restrict__ Xh,
                                                  const _Float16* __restrict__ Xl,
                                                  _Float16* __restrict__ Gh,
                                                  _Float16* __restrict__ Gl, int L) {
  __shared__ _Float16 sA[2][128][40];
  __shared__ _Float16 sX[2][4][128][8];
  const int tid = threadIdx.x;
  const int lane = tid & 63;
  const int wid = tid >> 6;
  const int wm = (wid >> 1) * 64, wn = (wid & 1) * 64;
  const int bm = blockIdx.y * 128;
  const int bl = blockIdx.x * 128;
  const int l15 = lane & 15, l4 = lane >> 4;

  f32x4 acc[4][4] = {};

  const int xlp = (tid & 63) * 2;
  const int xko = tid >> 6;

  for (int k0 = 0; k0 < KPAD; k0 += 32) {
    __syncthreads();
#pragma unroll
    for (int p = 0; p < 2; ++p) {
      int i = tid + p * 256;
      int m = i >> 2, k8 = (i & 3) * 8;
      *(half8*)&sA[0][m][k8] = *(const half8*)&Ah[(size_t)(bm + m) * KPAD + k0 + k8];
      *(half8*)&sA[1][m][k8] = *(const half8*)&Al[(size_t)(bm + m) * KPAD + k0 + k8];
    }
    {
      int gl = bl + xlp;
      int kb = k0 + xko * 8;
#pragma unroll
      for (int buf = 0; buf < 2; ++buf) {
        const _Float16* Xp = buf ? Xl : Xh;
        unsigned int v[8];
#pragma unroll
        for (int j = 0; j < 8; ++j)
          v[j] = *(const unsigned int*)&Xp[(size_t)(kb + j) * L + gl];
        short8 lo, hi;
#pragma unroll
        for (int j = 0; j < 8; ++j) {
          lo[j] = (short)(v[j] & 0xFFFFu);
          hi[j] = (short)(v[j] >> 16);
        }
        *(short8*)&sX[buf][xko][xlp][0] = lo;
        *(short8*)&sX[buf][xko][xlp + 1][0] = hi;
      }
    }
    __syncthreads();
    half8 afh[4], afl[4], bfh[4], bfl[4];
#pragma unroll
    for (int mi = 0; mi < 4; ++mi) {
      afh[mi] = *(half8*)&sA[0][wm + mi * 16 + l15][l4 * 8];
      afl[mi] = *(half8*)&sA[1][wm + mi * 16 + l15][l4 * 8];
    }
#pragma unroll
    for (int ni = 0; ni < 4; ++ni) {
      bfh[ni] = *(half8*)&sX[0][l4][wn + ni * 16 + l15][0];
      bfl[ni] = *(half8*)&sX[1][l4][wn + ni * 16 + l15][0];
    }
#pragma unroll
    for (int mi = 0; mi < 4; ++mi)
#pragma unroll
      for (int ni = 0; ni < 4; ++ni) {
        acc[mi][ni] = __builtin_amdgcn_mfma_f32_16x16x32_f16(afh[mi], bfh[ni],
                                                             acc[mi][ni], 0, 0, 0);
        acc[mi][ni] = __builtin_amdgcn_mfma_f32_16x16x32_f16(afh[mi], bfl[ni],
                                                             acc[mi][ni], 0, 0, 0);
        acc[mi][ni] = __builtin_amdgcn_mfma_f32_16x16x32_f16(afl[mi], bfh[ni],
                                                             acc[mi][ni], 0, 0, 0);
      }
  }
#pragma unroll
  for (int mi = 0; mi < 4; ++mi) {
    int row0 = bm + wm + mi * 16 + l4 * 4;
#pragma unroll
    for (int ni = 0; ni < 4; ++ni) {
      int col = bl + wn + ni * 16 + l15;
#pragma unroll
      for (int r = 0; r < 4; ++r) {
        int row = row0 + r;
        if (row < NN)
          split_f16(acc[mi][ni][r], &Gh[(size_t)row * L + col],
                    &Gl[(size_t)row * L + col]);
      }
    }
  }
}

// -------- build Xs: all 12 steps' x, octet-major [n][t][b][8] (j=0 only) -----
__global__ __launch_bounds__(256) void srcall_kernel(const float* __restrict__ src,
                                                     _Float16* __restrict__ Xsh,
                                                     _Float16* __restrict__ Xsl) {
  int i = blockIdx.x * 256 + threadIdx.x;
  if (i >= NN * BB * TT) return;
  int t = i % TT;
  int nb = i / TT;
  int b = nb & 63, n = nb >> 6;
  float v = src[((size_t)b * TT + t) * NN + n];
  size_t idx = (size_t)n * (TT * 512) + (size_t)t * 512 + (size_t)b * 8;
  split_f16(v, &Xsh[idx], &Xsl[idx]);
}

// -------- one-time per-node weight gen (t-invariant!) ------------------------
// Writes split-f16 weights in exactly the gconv LDS tile layout:
// per (node n, o-chunk oc): [KOW][OW][8] halves, flat 16B-aligned.
template <int CS, int CIN, int XSPLIT, int OW, int COUT>
__global__ __launch_bounds__(256) void wgen_pre(const float* __restrict__ E,
                                                const float* __restrict__ wpool,
                                                _Float16* __restrict__ Wh,
                                                _Float16* __restrict__ Wl) {
  constexpr int C = COUT / OW;
  constexpr int KD = 2 * CS;
  constexpr int KOW = KD / 8;
  const int bid = blockIdx.x;
  const int n = bid / C;
  const int oc = bid % C;
  if (n >= NN) return;
  const int och = oc * OW;
  const int tid = threadIdx.x;
  __shared__ float sE[EMB];
  if (tid < EMB) sE[tid] = E[n * EMB + tid];
  __syncthreads();
  _Float16* bh = Wh + ((size_t)n * C + oc) * ((size_t)KOW * OW * 8);
  _Float16* bl = Wl + ((size_t)n * C + oc) * ((size_t)KOW * OW * 8);
  const int o = tid & (OW - 1);
  for (int ko = tid / OW; ko < KOW; ko += 256 / OW) {
    half8 hv, lv;
#pragma unroll
    for (int j = 0; j < 8; ++j) {
      const int k = ko * 8 + j;
      const int kk = (k >= CS) ? 1 : 0;
      const int kc = k - kk * CS;
      int ii;
      if (CS == CIN) ii = kc;
      else ii = (kc == 0) ? 0 : ((kc >= XSPLIT) ? kc - XSPLIT + 1 : -1);
      float w = 0.0f;
      if (ii >= 0) {
        const float* wp = wpool + ((size_t)kk * CIN + ii) * COUT + och + o;
#pragma unroll
        for (int d = 0; d < EMB; ++d)
          w += sE[d] * wp[(size_t)d * (2 * CIN * COUT)];
      }
      _Float16 hh = (_Float16)w;
      hv[j] = hh;
      lv[j] = (_Float16)(w - (float)hh);
    }
    *(half8*)&bh[((size_t)ko * OW + o) * 8] = hv;
    *(half8*)&bl[((size_t)ko * OW + o) * 8] = lv;
  }
}

// -------- fused per-node gconv, NODE-PAIR batched ---------------------------
// Two nodes per block (nA = 2p, nB = 2p+1): one wpool read serves both nodes'
// W-gen (halves W-regen L2 traffic), and the 4 waves partition rows disjointly
// (waves 0,1 -> node A rows 0-31/32-63; waves 2,3 -> node B), eliminating the
// duplicated A-operand reads of the old wn-split mapping.
// h-state lives ONLY in X1a split-f16 (octets: layer0 ch 0-63, layer1 ch 64-127);
// epilogues reconstruct h = hi + lo (~2^-22 rel err).
// W source: PWh/PWl precomputed tiles (wgen_pre layout) if non-null, else
// batched fused gen. GATE: z-half -> z*h into XA (=Xz); r-half -> ZRout.
// !GATE: GRU update written as split-f16 into XA (=X1a).
template <int CS, int CIN, int XSPLIT, int OW, bool GATE>
__global__ __launch_bounds__(256) void gconv_fused(
    const _Float16* __restrict__ IXh, const _Float16* __restrict__ IXl, int sIX, int oIX,
    const _Float16* __restrict__ IZh, const _Float16* __restrict__ IZl, int sIZ, int oIZ,
    const _Float16* __restrict__ DXh, const _Float16* __restrict__ DXl, int sDX, int oDX,
    const _Float16* __restrict__ DZh, const _Float16* __restrict__ DZl, int sDZ, int oDZ,
    const float* __restrict__ E, const float* __restrict__ wpool,
    const float* __restrict__ bpool, const float* __restrict__ ZRin,
    const _Float16* __restrict__ Hh, const _Float16* __restrict__ Hl, int hb,
    float* __restrict__ ZRout,
    _Float16* __restrict__ XAh, _Float16* __restrict__ XAl, int csA, int cbA,
    const _Float16* __restrict__ PWh, const _Float16* __restrict__ PWl) {
  constexpr int COUT = GATE ? 128 : 64;
  constexpr int C = COUT / OW;         // o-chunks per node
  constexpr int KD = 2 * CS;
  constexpr int KP = (KD + 31) & ~31;  // 160 / 256 (MFMA loop extent)
  constexpr int KOW = KD / 8;          // 18 / 32 (W octets actually stored)
  // XCD swizzle decode over node-pairs
  const int bid = blockIdx.x;
  const int xcd = bid & 7;
  const int rest = bid >> 3;
  const int oc = rest % C;
  const int pq = rest / C;
  const int p = pq * 8 + xcd;
  const int nA = p * 2;
  if (nA >= NN) return;
  const int och = oc * OW;
  const int tid = threadIdx.x;
  const int lane = tid & 63, wid = tid >> 6;
  const int ns = wid >> 1;          // wave's node slot (0/1)
  const int wm = (wid & 1) * 32;    // row half within node
  const int l15 = lane & 15, l4 = lane >> 4;
  const int myn = nA + ns;          // may be >= NN for odd tail
  const int anode = (myn < NN) ? myn : nA;  // safe address node

  __shared__ float sE[2][EMB];
  __shared__ float sB[2][OW];
  __shared__ _Float16 sWh[2][KOW * OW * 8];
  __shared__ _Float16 sWl[2][KOW * OW * 8];

  if (tid < 2 * EMB) {
    const int s = tid / EMB, d = tid - s * EMB;
    const int node = nA + s;
    sE[s][d] = (node < NN) ? E[node * EMB + d] : 0.0f;
  }
  __syncthreads();

  // ---- W: stream precomputed tiles, or batched fused gen --------------------
  if (PWh != nullptr) {
    for (int i = tid; i < 2 * KOW * OW; i += 256) {
      const int s = i / (KOW * OW);
      const int r = i - s * (KOW * OW);
      const int node = nA + s;
      half8 hv = (half8)(_Float16)0.f, lv = (half8)(_Float16)0.f;
      if (node < NN) {
        const size_t wb =
            ((size_t)node * C + oc) * ((size_t)KOW * OW * 8) + (size_t)r * 8;
        hv = *(const half8*)&PWh[wb];
        lv = *(const half8*)&PWl[wb];
      }
      *(half8*)&sWh[s][(size_t)r * 8] = hv;
      *(half8*)&sWl[s][(size_t)r * 8] = lv;
    }
  } else {
    const int o = tid & (OW - 1);
    for (int ko = tid / OW; ko < KOW; ko += 256 / OW) {
      half8 hv0, lv0, hv1, lv1;
#pragma unroll
      for (int j = 0; j < 8; ++j) {
        const int k = ko * 8 + j;
        const int kk = (k >= CS) ? 1 : 0;
        const int kc = k - kk * CS;
        int ii;
        if (CS == CIN) ii = kc;
        else ii = (kc == 0) ? 0 : ((kc >= XSPLIT) ? kc - XSPLIT + 1 : -1);
        float w0 = 0.0f, w1 = 0.0f;
        if (ii >= 0) {
          const float* wp = wpool + ((size_t)kk * CIN + ii) * COUT + och + o;
#pragma unroll
          for (int d = 0; d < EMB; ++d) {
            const float wv = wp[(size_t)d * (2 * CIN * COUT)];
            w0 += sE[0][d] * wv;
            w1 += sE[1][d] * wv;
          }
        }
        _Float16 h0 = (_Float16)w0;
        hv0[j] = h0;
        lv0[j] = (_Float16)(w0 - (float)h0);
        _Float16 h1 = (_Float16)w1;
        hv1[j] = h1;
        lv1[j] = (_Float16)(w1 - (float)h1);
      }
      *(half8*)&sWh[0][((size_t)ko * OW + o) * 8] = hv0;
      *(half8*)&sWl[0][((size_t)ko * OW + o) * 8] = lv0;
      *(half8*)&sWh[1][((size_t)ko * OW + o) * 8] = hv1;
      *(half8*)&sWl[1][((size_t)ko * OW + o) * 8] = lv1;
    }
  }
  if (tid < 2 * OW) {
    const int s = tid / OW, o = tid - s * OW;
    float bb = 0.0f;
#pragma unroll
    for (int d = 0; d < EMB; ++d) bb += sE[s][d] * bpool[d * COUT + och + o];
    sB[s][o] = bb;
  }
  __syncthreads();

  // ---- MFMA: per-wave node, A-fragments coalesced half8 from global ---------
  const size_t bIX = (size_t)anode * sIX + (size_t)oIX * 512;
  const size_t bIZ = (size_t)anode * sIZ + (size_t)oIZ * 512;
  const size_t bDX = (size_t)anode * sDX + (size_t)oDX * 512;
  const size_t bDZ = (size_t)anode * sDZ + (size_t)oDZ * 512;
  f32x4 acc[2][2] = {};
  for (int k0 = 0; k0 < KP; k0 += 32) {
    const int kq = k0 + l4 * 8;
    half8 ah[2], al[2];
#pragma unroll
    for (int mt = 0; mt < 2; ++mt) {
      const int b = wm + mt * 16 + l15;
      if (kq < XSPLIT) {
        const size_t o = bIX + (size_t)(kq >> 3) * 512 + (size_t)b * 8;
        ah[mt] = *(const half8*)&IXh[o];
        al[mt] = *(const half8*)&IXl[o];
      } else if (kq < CS) {
        const size_t o = bIZ + (size_t)((kq - XSPLIT) >> 3) * 512 + (size_t)b * 8;
        ah[mt] = *(const half8*)&IZh[o];
        al[mt] = *(const half8*)&IZl[o];
      } else if (kq < CS + XSPLIT) {
        const size_t o = bDX + (size_t)((kq - CS) >> 3) * 512 + (size_t)b * 8;
        ah[mt] = *(const half8*)&DXh[o];
        al[mt] = *(const half8*)&DXl[o];
      } else if (kq < KD) {
        const size_t o =
            bDZ + (size_t)((kq - CS - XSPLIT) >> 3) * 512 + (size_t)b * 8;
        ah[mt] = *(const half8*)&DZh[o];
        al[mt] = *(const half8*)&DZl[o];
      } else {
        ah[mt] = (half8)(_Float16)0.f;
        al[mt] = (half8)(_Float16)0.f;
      }
    }
    const int koi = kq >> 3;
    half8 bh[2], bl[2];
#pragma unroll
    for (int nt = 0; nt < 2; ++nt) {
      const int ol = nt * 16 + l15;
      if (KP == KD || kq < KD) {
        bh[nt] = *(const half8*)&sWh[ns][((size_t)koi * OW + ol) * 8];
        bl[nt] = *(const half8*)&sWl[ns][((size_t)koi * OW + ol) * 8];
      } else {
        bh[nt] = (half8)(_Float16)0.f;
        bl[nt] = (half8)(_Float16)0.f;
      }
    }
#pragma unroll
    for (int mt = 0; mt < 2; ++mt)
#pragma unroll
      for (int nt = 0; nt < 2; ++nt) {
        acc[mt][nt] =
            __builtin_amdgcn_mfma_f32_16x16x32_f16(ah[mt], bh[nt], acc[mt][nt], 0, 0, 0);
        acc[mt][nt] =
            __builtin_amdgcn_mfma_f32_16x16x32_f16(ah[mt], bl[nt], acc[mt][nt], 0, 0, 0);
        acc[mt][nt] =
            __builtin_amdgcn_mfma_f32_16x16x32_f16(al[mt], bh[nt], acc[mt][nt], 0, 0, 0);
      }
  }

  // ---- epilogue (octet-major writes; h reconstructed from split-f16) --------
  if (myn < NN) {
#pragma unroll
    for (int mt = 0; mt < 2; ++mt) {
#pragma unroll
      for (int nt = 0; nt < 2; ++nt) {
        const int ol = nt * 16 + l15;
        const int og = och + ol;  // global output channel
        const float bias = sB[ns][ol];
#pragma unroll
        for (int r = 0; r < 4; ++r) {
          const int b = wm + mt * 16 + l4 * 4 + r;
          const size_t nb = (size_t)myn * 64 + b;
          const float v = acc[mt][nt][r] + bias;
          if constexpr (GATE) {
            const float s = 1.0f / (1.0f + expf(-v));
            if (og < 64) {  // z half: write z*h compact (cand GEMM input)
              const int ch = hb + og;
              const size_t ih = (size_t)myn * 8192 + (size_t)(ch >> 3) * 512 +
                                (size_t)b * 8 + (ch & 7);
              const float hold = (float)Hh[ih] + (float)Hl[ih];
              const float zh = s * hold;
              const int c2 = cbA + og;
              size_t ia = (size_t)myn * 64 * csA + (size_t)(c2 >> 3) * 512 +
                          (size_t)b * 8 + (c2 & 7);
              split_f16(zh, &XAh[ia], &XAl[ia]);
            } else {  // r half
              ZRout[nb * 64 + (og - 64)] = s;
            }
          } else {
            const float hc = tanhf(v);
            const float rr = ZRin[nb * 64 + og];
            const int cA = cbA + og;
            const size_t ia = (size_t)myn * 64 * csA + (size_t)(cA >> 3) * 512 +
                              (size_t)b * 8 + (cA & 7);
            const float hold = (float)XAh[ia] + (float)XAl[ia];
            const float hn = rr * hold + (1.0f - rr) * hc;
            split_f16(hn, &XAh[ia], &XAl[ia]);
          }
        }
      }
    }
  }
}

// ---------------- output head (h1 from X1a octets 8-15) ----------------------
__global__ __launch_bounds__(256) void head_kernel(const _Float16* __restrict__ Hh,
                                                   const _Float16* __restrict__ Hl,
                                                   const float* __restrict__ cw,
                                                   const float* __restrict__ cb,
                                                   float* __restrict__ out) {
  int i = blockIdx.x * 256 + threadIdx.x;
  if (i >= BB * NN) return;
  int n = i % NN, b = i / NN;
  float hv[64];
#pragma unroll
  for (int j = 0; j < 64; ++j) {
    const int c = 64 + j;
    const size_t ia =
        (size_t)n * 8192 + (size_t)(c >> 3) * 512 + (size_t)b * 8 + (c & 7);
    hv[j] = (float)Hh[ia] + (float)Hl[ia];
  }
  for (int o = 0; o < 12; ++o) {
    float s = cb[o];
#pragma unroll
    for (int j = 0; j < 64; ++j) s += hv[j] * cw[o * 64 + j];
    out[((size_t)b * 12 + o) * NN + n] = s;
  }
}

__global__ __launch_bounds__(256) void zero_u16(unsigned short* __restrict__ p,
                                                size_t count) {
  size_t i = (size_t)blockIdx.x * 256 + threadIdx.x;
  if (i < count) p[i] = 0;
}

extern "C" void kernel_launch(void* const* d_in, const int* in_sizes, int n_in,
                              void* d_out, int out_size, void* d_ws, size_t ws_size,
                              hipStream_t stream) {
  const float* src = (const float*)d_in[0];
  const float* E = (const float*)d_in[1];
  const float* w0g = (const float*)d_in[2];
  const float* b0g = (const float*)d_in[3];
  const float* w0c = (const float*)d_in[4];
  const float* b0c = (const float*)d_in[5];
  const float* w1g = (const float*)d_in[6];
  const float* b1g = (const float*)d_in[7];
  const float* w1c = (const float*)d_in[8];
  const float* b1c = (const float*)d_in[9];
  const float* cw = (const float*)d_in[10];
  const float* cb = (const float*)d_in[11];
  float* out = (float*)d_out;
  float* ws = (float*)d_ws;

  size_t off = 0;
  auto alloc = [&](size_t cnt) {  // cnt in floats
    float* p = ws + off;
    off += (cnt + 63) & ~(size_t)63;
    return p;
  };
  const int LS = TT * 512;  // 6144 (12 t-octets)
  const int L1 = 64 * 128;  // 8192 (16 octets)
  const int LZ = 64 * 64;   // 4096 (8 octets)
  _Float16* Ah = (_Float16*)alloc((size_t)KPAD * KPAD / 2);
  _Float16* Al = (_Float16*)alloc((size_t)KPAD * KPAD / 2);
  // contiguous zero span: Xs, Gx, X1a, Xz, Gl1, Gz (hi/lo pairs)
  _Float16* Xsh = (_Float16*)alloc((size_t)KPAD * LS / 2);
  _Float16* Xsl = (_Float16*)alloc((size_t)KPAD * LS / 2);
  _Float16* Gxh = (_Float16*)alloc((size_t)KPAD * LS / 2);
  _Float16* Gxl = (_Float16*)alloc((size_t)KPAD * LS / 2);
  _Float16* X1ah = (_Float16*)alloc((size_t)KPAD * L1 / 2);
  _Float16* X1al = (_Float16*)alloc((size_t)KPAD * L1 / 2);
  _Float16* Xzh = (_Float16*)alloc((size_t)KPAD * LZ / 2);
  _Float16* Xzl = (_Float16*)alloc((size_t)KPAD * LZ / 2);
  _Float16* Gl1h = (_Float16*)alloc((size_t)KPAD * L1 / 2);
  _Float16* Gl1l = (_Float16*)alloc((size_t)KPAD * L1 / 2);
  _Float16* Gzh = (_Float16*)alloc((size_t)KPAD * LZ / 2);
  _Float16* Gzl = (_Float16*)alloc((size_t)KPAD * LZ / 2);
  float* ZR = alloc((size_t)NN * BB * 64);
  if (off * sizeof(float) > ws_size) return;  // ws too small: fail loud (zeros)

  // ---- tiered precomputed per-node weights (t-invariant) ----
  // Flavor f cost (floats): g0 NN*18432, c0 NN*9216, g1 NN*32768, c1 NN*16384.
  // Enumerate all 16 subsets, pick max total that fits (graceful degradation).
  const size_t wsfl = ws_size / sizeof(float);
  const size_t whalves[4] = {(size_t)NN * 18432, (size_t)NN * 9216,
                             (size_t)NN * 32768, (size_t)NN * 16384};
  const size_t avail = (wsfl > off) ? (wsfl - off) : 0;
  int best = 0;
  size_t bestsz = 0;
  for (int s = 1; s < 16; ++s) {
    size_t tot = 0;
    for (int f = 0; f < 4; ++f)
      if (s & (1 << f)) tot += whalves[f] + 128;  // +alignment slack
    if (tot <= avail && tot > bestsz) {
      bestsz = tot;
      best = s;
    }
  }
  _Float16 *W0gh = nullptr, *W0gl = nullptr, *W0ch = nullptr, *W0cl = nullptr;
  _Float16 *W1gh = nullptr, *W1gl = nullptr, *W1ch = nullptr, *W1cl = nullptr;
  if (best & 1) {
    W0gh = (_Float16*)alloc(whalves[0] / 2);
    W0gl = (_Float16*)alloc(whalves[0] / 2);
  }
  if (best & 2) {
    W0ch = (_Float16*)alloc(whalves[1] / 2);
    W0cl = (_Float16*)alloc(whalves[1] / 2);
  }
  if (best & 4) {
    W1gh = (_Float16*)alloc(whalves[2] / 2);
    W1gl = (_Float16*)alloc(whalves[2] / 2);
  }
  if (best & 8) {
    W1ch = (_Float16*)alloc(whalves[3] / 2);
    W1cl = (_Float16*)alloc(whalves[3] / 2);
  }

  adj_kernel<<<NN, 256, 0, stream>>>(E, Ah, Al);
  {
    size_t cx = (size_t)2 * KPAD * (LS + LS + L1 + LZ + L1 + LZ);  // halves
    zero_u16<<<(int)((cx + 255) / 256), 256, 0, stream>>>((unsigned short*)Xsh, cx);
  }
  // Pre-loop: Gx = A @ Xs  (all 12 steps' x diffused, once)
  srcall_kernel<<<(NN * BB * TT + 255) / 256, 256, 0, stream>>>(src, Xsh, Xsl);
  mfma_gemm3<<<dim3(LS / 128, 7), 256, 0, stream>>>(Ah, Al, Xsh, Xsl, Gxh, Gxl, LS);
  // One-time W precompute for fitted flavors (kills per-step W-gen L2 storm)
  if (W0gh) wgen_pre<72, 65, 8, 32, 128><<<NN * 4, 256, 0, stream>>>(E, w0g, W0gh, W0gl);
  if (W0ch) wgen_pre<72, 65, 8, 32, 64><<<NN * 2, 256, 0, stream>>>(E, w0c, W0ch, W0cl);
  if (W1gh) wgen_pre<128, 128, 64, 32, 128><<<NN * 4, 256, 0, stream>>>(E, w1g, W1gh, W1gl);
  if (W1ch) wgen_pre<128, 128, 64, 32, 64><<<NN * 2, 256, 0, stream>>>(E, w1c, W1ch, W1cl);

  const int gx1 = L1 / 128;  // 64
  const int gxz = LZ / 128;  // 32
  // node-pair grid: 442 pairs padded to 448 (multiple of 8 for XCD swizzle)
  const int PQ = (((NN + 1) / 2 + 7) / 8) * 8;  // 448
  const int g_gate = PQ * 4;                    // C=4 chunks (OW=32, COUT=128)
  const int g_cand = PQ * 2;                    // C=2 chunks (OW=32, COUT=64)
  for (int t = 0; t < TT; ++t) {
    // ---- layer 0: identity x <- Xs[t], h0 <- X1a octets 0-7;
    //      diffused x <- Gx[t], diffused h0 <- Gl1 octets 0-7 (step t-1) ----
    gconv_fused<72, 65, 8, 32, true><<<g_gate, 256, 0, stream>>>(
        Xsh, Xsl, LS, t, X1ah, X1al, L1, 0, Gxh, Gxl, LS, t, Gl1h, Gl1l, L1, 0,
        E, w0g, b0g, nullptr, X1ah, X1al, 0, ZR, Xzh, Xzl, 64, 0, W0gh, W0gl);
    mfma_gemm3<<<dim3(gxz, 7), 256, 0, stream>>>(Ah, Al, Xzh, Xzl, Gzh, Gzl, LZ);
    gconv_fused<72, 65, 8, 32, false><<<g_cand, 256, 0, stream>>>(
        Xsh, Xsl, LS, t, Xzh, Xzl, LZ, 0, Gxh, Gxl, LS, t, Gzh, Gzl, LZ, 0,
        E, w0c, b0c, ZR, nullptr, nullptr, 0, nullptr, X1ah, X1al, 128, 0, W0ch, W0cl);
    // ---- layer 1: identity h0 <- X1a oct 0-7, h1 <- X1a oct 8-15 ----
    mfma_gemm3<<<dim3(gx1, 7), 256, 0, stream>>>(Ah, Al, X1ah, X1al, Gl1h, Gl1l, L1);
    gconv_fused<128, 128, 64, 32, true><<<g_gate, 256, 0, stream>>>(
        X1ah, X1al, L1, 0, X1ah, X1al, L1, 8, Gl1h, Gl1l, L1, 0, Gl1h, Gl1l, L1, 8,
        E, w1g, b1g, nullptr, X1ah, X1al, 64, ZR, Xzh, Xzl, 64, 0, W1gh, W1gl);
    mfma_gemm3<<<dim3(gxz, 7), 256, 0, stream>>>(Ah, Al, Xzh, Xzl, Gzh, Gzl, LZ);
    gconv_fused<128, 128, 64, 32, false><<<g_cand, 256, 0, stream>>>(
        X1ah, X1al, L1, 0, Xzh, Xzl, LZ, 0, Gl1h, Gl1l, L1, 0, Gzh, Gzl, LZ, 0,
        E, w1c, b1c, ZR, nullptr, nullptr, 0, nullptr, X1ah, X1al, 128, 64, W1ch, W1cl);
  }
  head_kernel<<<(BB * NN + 255) / 256, 256, 0, stream>>>(X1ah, X1al, cw, cb, out);
}

// Round 4
// 3555.154 us; speedup vs baseline: 1.1260x; 1.0638x over previous
//
#include <hip/hip_runtime.h>
#include <cstddef>

#define NN 883
#define BB 64
#define TT 12
#define EMB 10
#define KPAD 896  // node dim padded to multiple of 128

typedef short short8 __attribute__((ext_vector_type(8)));
typedef _Float16 half8 __attribute__((ext_vector_type(8)));
typedef float f32x4 __attribute__((ext_vector_type(4)));

__device__ __forceinline__ void split_f16(float v, _Float16* hp, _Float16* lp) {
  _Float16 h = (_Float16)v;
  *hp = h;
  *lp = (_Float16)(v - (float)h);
}

// -------- adjacency: A = softmax(relu(E E^T), axis=1), emitted as f16 hi/lo --
__global__ __launch_bounds__(256) void adj_kernel(const float* __restrict__ E,
                                                  _Float16* __restrict__ Ah,
                                                  _Float16* __restrict__ Al) {
  const int n = blockIdx.x;
  const int tid = threadIdx.x;
  __shared__ float sE[EMB];
  __shared__ float sred[256];
  if (tid < EMB) sE[tid] = E[n * EMB + tid];
  __syncthreads();
  float d[4];
  float lmax = 0.0f;
#pragma unroll
  for (int q = 0; q < 4; ++q) {
    int m = tid + q * 256;
    d[q] = 0.0f;
    if (m < NN) {
      float s = 0.0f;
#pragma unroll
      for (int e = 0; e < EMB; ++e) s += sE[e] * E[m * EMB + e];
      d[q] = fmaxf(s, 0.0f);
      lmax = fmaxf(lmax, d[q]);
    }
  }
  sred[tid] = lmax;
  __syncthreads();
  for (int s = 128; s > 0; s >>= 1) {
    if (tid < s) sred[tid] = fmaxf(sred[tid], sred[tid + s]);
    __syncthreads();
  }
  const float mx = sred[0];
  __syncthreads();
  float lsum = 0.0f;
#pragma unroll
  for (int q = 0; q < 4; ++q) {
    int m = tid + q * 256;
    if (m < NN) {
      d[q] = expf(d[q] - mx);
      lsum += d[q];
    }
  }
  sred[tid] = lsum;
  __syncthreads();
  for (int s = 128; s > 0; s >>= 1) {
    if (tid < s) sred[tid] += sred[tid + s];
    __syncthreads();
  }
  const float inv = 1.0f / sred[0];
#pragma unroll
  for (int q = 0; q < 4; ++q) {
    int m = tid + q * 256;
    if (m < KPAD) {
      float v = (m < NN) ? d[q] * inv : 0.0f;
      split_f16(v, &Ah[(size_t)n * KPAD + m], &Al[(size_t)n * KPAD + m]);
    }
  }
}

// -------- 3-term split-f16 MFMA GEMM; output written as split f16 ------------
__global__ __launch_bounds__(256) void mfma_gemm3(const _Float16* __restrict__ Ah,
                                                  const _Float16* __restrict__ Al,
                                                  const _Float16* __restrict__ Xh,
                                                  const _Float16* __restrict__ Xl,
                                                  _Float16* __restrict__ Gh,
                                                  _Float16* __restrict__ Gl, int L) {
  __shared__ _Float16 sA[2][128][40];
  __shared__ _Float16 sX[2][4][128][8];
  const int tid = threadIdx.x;
  const int lane = tid & 63;
  const int wid = tid >> 6;
  const int wm = (wid >> 1) * 64, wn = (wid & 1) * 64;
  const int bm = blockIdx.y * 128;
  const int bl = blockIdx.x * 128;
  const int l15 = lane & 15, l4 = lane >> 4;

  f32x4 acc[4][4] = {};

  const int xlp = (tid & 63) * 2;
  const int xko = tid >> 6;

  for (int k0 = 0; k0 < KPAD; k0 += 32) {
    __syncthreads();
#pragma unroll
    for (int p = 0; p < 2; ++p) {
      int i = tid + p * 256;
      int m = i >> 2, k8 = (i & 3) * 8;
      *(half8*)&sA[0][m][k8] = *(const half8*)&Ah[(size_t)(bm + m) * KPAD + k0 + k8];
      *(half8*)&sA[1][m][k8] = *(const half8*)&Al[(size_t)(bm + m) * KPAD + k0 + k8];
    }
    {
      int gl = bl + xlp;
      int kb = k0 + xko * 8;
#pragma unroll
      for (int buf = 0; buf < 2; ++buf) {
        const _Float16* Xp = buf ? Xl : Xh;
        unsigned int v[8];
#pragma unroll
        for (int j = 0; j < 8; ++j)
          v[j] = *(const unsigned int*)&Xp[(size_t)(kb + j) * L + gl];
        short8 lo, hi;
#pragma unroll
        for (int j = 0; j < 8; ++j) {
          lo[j] = (short)(v[j] & 0xFFFFu);
          hi[j] = (short)(v[j] >> 16);
        }
        *(short8*)&sX[buf][xko][xlp][0] = lo;
        *(short8*)&sX[buf][xko][xlp + 1][0] = hi;
      }
    }
    __syncthreads();
    half8 afh[4], afl[4], bfh[4], bfl[4];
#pragma unroll
    for (int mi = 0; mi < 4; ++mi) {
      afh[mi] = *(half8*)&sA[0][wm + mi * 16 + l15][l4 * 8];
      afl[mi] = *(half8*)&sA[1][wm + mi * 16 + l15][l4 * 8];
    }
#pragma unroll
    for (int ni = 0; ni < 4; ++ni) {
      bfh[ni] = *(half8*)&sX[0][l4][wn + ni * 16 + l15][0];
      bfl[ni] = *(half8*)&sX[1][l4][wn + ni * 16 + l15][0];
    }
#pragma unroll
    for (int mi = 0; mi < 4; ++mi)
#pragma unroll
      for (int ni = 0; ni < 4; ++ni) {
        acc[mi][ni] = __builtin_amdgcn_mfma_f32_16x16x32_f16(afh[mi], bfh[ni],
                                                             acc[mi][ni], 0, 0, 0);
        acc[mi][ni] = __builtin_amdgcn_mfma_f32_16x16x32_f16(afh[mi], bfl[ni],
                                                             acc[mi][ni], 0, 0, 0);
        acc[mi][ni] = __builtin_amdgcn_mfma_f32_16x16x32_f16(afl[mi], bfh[ni],
                                                             acc[mi][ni], 0, 0, 0);
      }
  }
#pragma unroll
  for (int mi = 0; mi < 4; ++mi) {
    int row0 = bm + wm + mi * 16 + l4 * 4;
#pragma unroll
    for (int ni = 0; ni < 4; ++ni) {
      int col = bl + wn + ni * 16 + l15;
#pragma unroll
      for (int r = 0; r < 4; ++r) {
        int row = row0 + r;
        if (row < NN)
          split_f16(acc[mi][ni][r], &Gh[(size_t)row * L + col],
                    &Gl[(size_t)row * L + col]);
      }
    }
  }
}

// -------- build Xs: all 12 steps' x, octet-major [n][t][b][8] ----------------
// Writes the FULL octet (j=0 value, j=1..7 zero) so Xs needs no pre-zeroing
// except pad rows. b-fastest thread mapping -> coalesced 16B stores.
__global__ __launch_bounds__(256) void srcall_kernel(const float* __restrict__ src,
                                                     _Float16* __restrict__ Xsh,
                                                     _Float16* __restrict__ Xsl) {
  int i = blockIdx.x * 256 + threadIdx.x;
  if (i >= NN * BB * TT) return;
  int b = i & 63;
  int rest = i >> 6;
  int t = rest % TT;
  int n = rest / TT;
  float v = src[((size_t)b * TT + t) * NN + n];
  size_t idx = (size_t)n * (TT * 512) + (size_t)t * 512 + (size_t)b * 8;
  half8 hv = (half8)(_Float16)0.f, lv = (half8)(_Float16)0.f;
  _Float16 hh = (_Float16)v;
  hv[0] = hh;
  lv[0] = (_Float16)(v - (float)hh);
  *(half8*)&Xsh[idx] = hv;
  *(half8*)&Xsl[idx] = lv;
}

// -------- one-time per-node weight gen (t-invariant!) ------------------------
// Writes split-f16 weights in exactly the gconv LDS tile layout:
// per (node n, o-chunk oc): [KOW][OW][8] halves, flat 16B-aligned.
template <int CS, int CIN, int XSPLIT, int OW, int COUT>
__global__ __launch_bounds__(256) void wgen_pre(const float* __restrict__ E,
                                                const float* __restrict__ wpool,
                                                _Float16* __restrict__ Wh,
                                                _Float16* __restrict__ Wl) {
  constexpr int C = COUT / OW;
  constexpr int KD = 2 * CS;
  constexpr int KOW = KD / 8;
  const int bid = blockIdx.x;
  const int n = bid / C;
  const int oc = bid % C;
  if (n >= NN) return;
  const int och = oc * OW;
  const int tid = threadIdx.x;
  __shared__ float sE[EMB];
  if (tid < EMB) sE[tid] = E[n * EMB + tid];
  __syncthreads();
  _Float16* bh = Wh + ((size_t)n * C + oc) * ((size_t)KOW * OW * 8);
  _Float16* bl = Wl + ((size_t)n * C + oc) * ((size_t)KOW * OW * 8);
  const int o = tid & (OW - 1);
  for (int ko = tid / OW; ko < KOW; ko += 256 / OW) {
    half8 hv, lv;
#pragma unroll
    for (int j = 0; j < 8; ++j) {
      const int k = ko * 8 + j;
      const int kk = (k >= CS) ? 1 : 0;
      const int kc = k - kk * CS;
      int ii;
      if (CS == CIN) ii = kc;
      else ii = (kc == 0) ? 0 : ((kc >= XSPLIT) ? kc - XSPLIT + 1 : -1);
      float w = 0.0f;
      if (ii >= 0) {
        const float* wp = wpool + ((size_t)kk * CIN + ii) * COUT + och + o;
#pragma unroll
        for (int d = 0; d < EMB; ++d)
          w += sE[d] * wp[(size_t)d * (2 * CIN * COUT)];
      }
      _Float16 hh = (_Float16)w;
      hv[j] = hh;
      lv[j] = (_Float16)(w - (float)hh);
    }
    *(half8*)&bh[((size_t)ko * OW + o) * 8] = hv;
    *(half8*)&bl[((size_t)ko * OW + o) * 8] = lv;
  }
}

// -------- fused per-node gconv, NODE-PAIR batched ---------------------------
// Two nodes per block (nA = 2p, nB = 2p+1); waves partition rows disjointly
// (waves 0,1 -> node A rows 0-31/32-63; waves 2,3 -> node B).
// h-state lives ONLY in X1a split-f16; epilogues reconstruct h = hi + lo.
// PRE=true: W fragments read DIRECTLY from precomputed global tiles in the
// k-loop (coalesced 256B per 16-lane group) -> no W LDS, no staging barrier,
// ~0.4KB LDS -> ~5 blocks/CU occupancy (vs 2 with the 64KB LDS tile).
// PRE=false: legacy batched fused W-gen into LDS (wpool is L2-resident).
// GATE: z-half -> z*h into XA (=Xz); r-half -> ZRout.
// !GATE: GRU update written as split-f16 into XA (=X1a).
template <int CS, int CIN, int XSPLIT, int OW, bool GATE, bool PRE>
__global__ __launch_bounds__(256) void gconv_fused(
    const _Float16* __restrict__ IXh, const _Float16* __restrict__ IXl, int sIX, int oIX,
    const _Float16* __restrict__ IZh, const _Float16* __restrict__ IZl, int sIZ, int oIZ,
    const _Float16* __restrict__ DXh, const _Float16* __restrict__ DXl, int sDX, int oDX,
    const _Float16* __restrict__ DZh, const _Float16* __restrict__ DZl, int sDZ, int oDZ,
    const float* __restrict__ E, const float* __restrict__ wpool,
    const float* __restrict__ bpool, const float* __restrict__ ZRin,
    const _Float16* __restrict__ Hh, const _Float16* __restrict__ Hl, int hb,
    float* __restrict__ ZRout,
    _Float16* __restrict__ XAh, _Float16* __restrict__ XAl, int csA, int cbA,
    const _Float16* __restrict__ PWh, const _Float16* __restrict__ PWl) {
  constexpr int COUT = GATE ? 128 : 64;
  constexpr int C = COUT / OW;         // o-chunks per node
  constexpr int KD = 2 * CS;
  constexpr int KP = (KD + 31) & ~31;  // 160 / 256 (MFMA loop extent)
  constexpr int KOW = KD / 8;          // 18 / 32 (W octets actually stored)
  // XCD swizzle decode over node-pairs
  const int bid = blockIdx.x;
  const int xcd = bid & 7;
  const int rest = bid >> 3;
  const int oc = rest % C;
  const int pq = rest / C;
  const int p = pq * 8 + xcd;
  const int nA = p * 2;
  if (nA >= NN) return;
  const int och = oc * OW;
  const int tid = threadIdx.x;
  const int lane = tid & 63, wid = tid >> 6;
  const int ns = wid >> 1;          // wave's node slot (0/1)
  const int wm = (wid & 1) * 32;    // row half within node
  const int l15 = lane & 15, l4 = lane >> 4;
  const int myn = nA + ns;          // may be >= NN for odd tail
  const int anode = (myn < NN) ? myn : nA;  // safe address node

  __shared__ float sE[2][EMB];
  __shared__ float sB[2][OW];
  __shared__ _Float16 sWh[PRE ? 8 : 2 * KOW * OW * 8];
  __shared__ _Float16 sWl[PRE ? 8 : 2 * KOW * OW * 8];

  if (tid < 2 * EMB) {
    const int s = tid / EMB, d = tid - s * EMB;
    const int node = nA + s;
    sE[s][d] = (node < NN) ? E[node * EMB + d] : 0.0f;
  }
  __syncthreads();

  // ---- W (regen fallback only): batched fused gen into LDS ------------------
  if constexpr (!PRE) {
    const int o = tid & (OW - 1);
    for (int ko = tid / OW; ko < KOW; ko += 256 / OW) {
      half8 hv0, lv0, hv1, lv1;
#pragma unroll
      for (int j = 0; j < 8; ++j) {
        const int k = ko * 8 + j;
        const int kk = (k >= CS) ? 1 : 0;
        const int kc = k - kk * CS;
        int ii;
        if (CS == CIN) ii = kc;
        else ii = (kc == 0) ? 0 : ((kc >= XSPLIT) ? kc - XSPLIT + 1 : -1);
        float w0 = 0.0f, w1 = 0.0f;
        if (ii >= 0) {
          const float* wp = wpool + ((size_t)kk * CIN + ii) * COUT + och + o;
#pragma unroll
          for (int d = 0; d < EMB; ++d) {
            const float wv = wp[(size_t)d * (2 * CIN * COUT)];
            w0 += sE[0][d] * wv;
            w1 += sE[1][d] * wv;
          }
        }
        _Float16 h0 = (_Float16)w0;
        hv0[j] = h0;
        lv0[j] = (_Float16)(w0 - (float)h0);
        _Float16 h1 = (_Float16)w1;
        hv1[j] = h1;
        lv1[j] = (_Float16)(w1 - (float)h1);
      }
      *(half8*)&sWh[((size_t)ko * OW + o) * 8] = hv0;
      *(half8*)&sWl[((size_t)ko * OW + o) * 8] = lv0;
      *(half8*)&sWh[(size_t)KOW * OW * 8 + ((size_t)ko * OW + o) * 8] = hv1;
      *(half8*)&sWl[(size_t)KOW * OW * 8 + ((size_t)ko * OW + o) * 8] = lv1;
    }
  }
  if (tid < 2 * OW) {
    const int s = tid / OW, o = tid - s * OW;
    float bb = 0.0f;
#pragma unroll
    for (int d = 0; d < EMB; ++d) bb += sE[s][d] * bpool[d * COUT + och + o];
    sB[s][o] = bb;
  }
  __syncthreads();

  // ---- MFMA: per-wave node, A-fragments coalesced half8 from global ---------
  const size_t bIX = (size_t)anode * sIX + (size_t)oIX * 512;
  const size_t bIZ = (size_t)anode * sIZ + (size_t)oIZ * 512;
  const size_t bDX = (size_t)anode * sDX + (size_t)oDX * 512;
  const size_t bDZ = (size_t)anode * sDZ + (size_t)oDZ * 512;
  const size_t wtile = (size_t)KOW * OW * 8;
  const size_t wbase = PRE ? ((size_t)anode * C + oc) * wtile : (size_t)ns * wtile;
  f32x4 acc[2][2] = {};
  for (int k0 = 0; k0 < KP; k0 += 32) {
    const int kq = k0 + l4 * 8;
    half8 ah[2], al[2];
#pragma unroll
    for (int mt = 0; mt < 2; ++mt) {
      const int b = wm + mt * 16 + l15;
      if (kq < XSPLIT) {
        const size_t o = bIX + (size_t)(kq >> 3) * 512 + (size_t)b * 8;
        ah[mt] = *(const half8*)&IXh[o];
        al[mt] = *(const half8*)&IXl[o];
      } else if (kq < CS) {
        const size_t o = bIZ + (size_t)((kq - XSPLIT) >> 3) * 512 + (size_t)b * 8;
        ah[mt] = *(const half8*)&IZh[o];
        al[mt] = *(const half8*)&IZl[o];
      } else if (kq < CS + XSPLIT) {
        const size_t o = bDX + (size_t)((kq - CS) >> 3) * 512 + (size_t)b * 8;
        ah[mt] = *(const half8*)&DXh[o];
        al[mt] = *(const half8*)&DXl[o];
      } else if (kq < KD) {
        const size_t o =
            bDZ + (size_t)((kq - CS - XSPLIT) >> 3) * 512 + (size_t)b * 8;
        ah[mt] = *(const half8*)&DZh[o];
        al[mt] = *(const half8*)&DZl[o];
      } else {
        ah[mt] = (half8)(_Float16)0.f;
        al[mt] = (half8)(_Float16)0.f;
      }
    }
    const int koi = kq >> 3;
    half8 bh[2], bl[2];
#pragma unroll
    for (int nt = 0; nt < 2; ++nt) {
      const int ol = nt * 16 + l15;
      if (KP == KD || kq < KD) {
        const size_t wo = wbase + ((size_t)koi * OW + ol) * 8;
        if constexpr (PRE) {
          bh[nt] = *(const half8*)&PWh[wo];
          bl[nt] = *(const half8*)&PWl[wo];
        } else {
          bh[nt] = *(const half8*)&sWh[wo];
          bl[nt] = *(const half8*)&sWl[wo];
        }
      } else {
        bh[nt] = (half8)(_Float16)0.f;
        bl[nt] = (half8)(_Float16)0.f;
      }
    }
#pragma unroll
    for (int mt = 0; mt < 2; ++mt)
#pragma unroll
      for (int nt = 0; nt < 2; ++nt) {
        acc[mt][nt] =
            __builtin_amdgcn_mfma_f32_16x16x32_f16(ah[mt], bh[nt], acc[mt][nt], 0, 0, 0);
        acc[mt][nt] =
            __builtin_amdgcn_mfma_f32_16x16x32_f16(ah[mt], bl[nt], acc[mt][nt], 0, 0, 0);
        acc[mt][nt] =
            __builtin_amdgcn_mfma_f32_16x16x32_f16(al[mt], bh[nt], acc[mt][nt], 0, 0, 0);
      }
  }

  // ---- epilogue (octet-major writes; h reconstructed from split-f16) --------
  if (myn < NN) {
#pragma unroll
    for (int mt = 0; mt < 2; ++mt) {
#pragma unroll
      for (int nt = 0; nt < 2; ++nt) {
        const int ol = nt * 16 + l15;
        const int og = och + ol;  // global output channel
        const float bias = sB[ns][ol];
#pragma unroll
        for (int r = 0; r < 4; ++r) {
          const int b = wm + mt * 16 + l4 * 4 + r;
          const size_t nb = (size_t)myn * 64 + b;
          const float v = acc[mt][nt][r] + bias;
          if constexpr (GATE) {
            const float s = 1.0f / (1.0f + expf(-v));
            if (og < 64) {  // z half: write z*h compact (cand GEMM input)
              const int ch = hb + og;
              const size_t ih = (size_t)myn * 8192 + (size_t)(ch >> 3) * 512 +
                                (size_t)b * 8 + (ch & 7);
              const float hold = (float)Hh[ih] + (float)Hl[ih];
              const float zh = s * hold;
              const int c2 = cbA + og;
              size_t ia = (size_t)myn * 64 * csA + (size_t)(c2 >> 3) * 512 +
                          (size_t)b * 8 + (c2 & 7);
              split_f16(zh, &XAh[ia], &XAl[ia]);
            } else {  // r half
              ZRout[nb * 64 + (og - 64)] = s;
            }
          } else {
            const float hc = tanhf(v);
            const float rr = ZRin[nb * 64 + og];
            const int cA = cbA + og;
            const size_t ia = (size_t)myn * 64 * csA + (size_t)(cA >> 3) * 512 +
                              (size_t)b * 8 + (cA & 7);
            const float hold = (float)XAh[ia] + (float)XAl[ia];
            const float hn = rr * hold + (1.0f - rr) * hc;
            split_f16(hn, &XAh[ia], &XAl[ia]);
          }
        }
      }
    }
  }
}

// ---------------- output head (h1 from X1a octets 8-15) ----------------------
__global__ __launch_bounds__(256) void head_kernel(const _Float16* __restrict__ Hh,
                                                   const _Float16* __restrict__ Hl,
                                                   const float* __restrict__ cw,
                                                   const float* __restrict__ cb,
                                                   float* __restrict__ out) {
  int i = blockIdx.x * 256 + threadIdx.x;
  if (i >= BB * NN) return;
  int n = i % NN, b = i / NN;
  float hv[64];
#pragma unroll
  for (int j = 0; j < 64; ++j) {
    const int c = 64 + j;
    const size_t ia =
        (size_t)n * 8192 + (size_t)(c >> 3) * 512 + (size_t)b * 8 + (c & 7);
    hv[j] = (float)Hh[ia] + (float)Hl[ia];
  }
  for (int o = 0; o < 12; ++o) {
    float s = cb[o];
#pragma unroll
    for (int j = 0; j < 64; ++j) s += hv[j] * cw[o * 64 + j];
    out[((size_t)b * 12 + o) * NN + n] = s;
  }
}

// 16B-per-thread zero (count in half8 units)
__global__ __launch_bounds__(256) void zero_h8(_Float16* __restrict__ p,
                                               size_t cnt8) {
  size_t i = (size_t)blockIdx.x * 256 + threadIdx.x;
  if (i < cnt8) *(half8*)&p[i * 8] = (half8)(_Float16)0.f;
}

extern "C" void kernel_launch(void* const* d_in, const int* in_sizes, int n_in,
                              void* d_out, int out_size, void* d_ws, size_t ws_size,
                              hipStream_t stream) {
  const float* src = (const float*)d_in[0];
  const float* E = (const float*)d_in[1];
  const float* w0g = (const float*)d_in[2];
  const float* b0g = (const float*)d_in[3];
  const float* w0c = (const float*)d_in[4];
  const float* b0c = (const float*)d_in[5];
  const float* w1g = (const float*)d_in[6];
  const float* b1g = (const float*)d_in[7];
  const float* w1c = (const float*)d_in[8];
  const float* b1c = (const float*)d_in[9];
  const float* cw = (const float*)d_in[10];
  const float* cb = (const float*)d_in[11];
  float* out = (float*)d_out;
  float* ws = (float*)d_ws;

  size_t off = 0;
  auto alloc = [&](size_t cnt) {  // cnt in floats
    float* p = ws + off;
    off += (cnt + 63) & ~(size_t)63;
    return p;
  };
  const int LS = TT * 512;  // 6144 (12 t-octets)
  const int L1 = 64 * 128;  // 8192 (16 octets)
  const int LZ = 64 * 64;   // 4096 (8 octets)
  _Float16* Ah = (_Float16*)alloc((size_t)KPAD * KPAD / 2);
  _Float16* Al = (_Float16*)alloc((size_t)KPAD * KPAD / 2);
  _Float16* Xsh = (_Float16*)alloc((size_t)KPAD * LS / 2);
  _Float16* Xsl = (_Float16*)alloc((size_t)KPAD * LS / 2);
  _Float16* Gxh = (_Float16*)alloc((size_t)KPAD * LS / 2);
  _Float16* Gxl = (_Float16*)alloc((size_t)KPAD * LS / 2);
  // contiguous zero span: X1a, Xz, Gl1 (hi/lo pairs)
  _Float16* X1ah = (_Float16*)alloc((size_t)KPAD * L1 / 2);
  _Float16* X1al = (_Float16*)alloc((size_t)KPAD * L1 / 2);
  _Float16* Xzh = (_Float16*)alloc((size_t)KPAD * LZ / 2);
  _Float16* Xzl = (_Float16*)alloc((size_t)KPAD * LZ / 2);
  _Float16* Gl1h = (_Float16*)alloc((size_t)KPAD * L1 / 2);
  _Float16* Gl1l = (_Float16*)alloc((size_t)KPAD * L1 / 2);
  _Float16* Gzh = (_Float16*)alloc((size_t)KPAD * LZ / 2);
  _Float16* Gzl = (_Float16*)alloc((size_t)KPAD * LZ / 2);
  float* ZR = alloc((size_t)NN * BB * 64);
  if (off * sizeof(float) > ws_size) return;  // ws too small: fail loud (zeros)

  // ---- tiered precomputed per-node weights (t-invariant) ----
  // Flavor f cost (floats): g0 NN*18432, c0 NN*9216, g1 NN*32768, c1 NN*16384.
  // Enumerate all 16 subsets, pick max total that fits (graceful degradation).
  const size_t wsfl = ws_size / sizeof(float);
  const size_t whalves[4] = {(size_t)NN * 18432, (size_t)NN * 9216,
                             (size_t)NN * 32768, (size_t)NN * 16384};
  const size_t avail = (wsfl > off) ? (wsfl - off) : 0;
  int best = 0;
  size_t bestsz = 0;
  for (int s = 1; s < 16; ++s) {
    size_t tot = 0;
    for (int f = 0; f < 4; ++f)
      if (s & (1 << f)) tot += whalves[f] + 128;  // +alignment slack
    if (tot <= avail && tot > bestsz) {
      bestsz = tot;
      best = s;
    }
  }
  _Float16 *W0gh = nullptr, *W0gl = nullptr, *W0ch = nullptr, *W0cl = nullptr;
  _Float16 *W1gh = nullptr, *W1gl = nullptr, *W1ch = nullptr, *W1cl = nullptr;
  if (best & 1) {
    W0gh = (_Float16*)alloc(whalves[0] / 2);
    W0gl = (_Float16*)alloc(whalves[0] / 2);
  }
  if (best & 2) {
    W0ch = (_Float16*)alloc(whalves[1] / 2);
    W0cl = (_Float16*)alloc(whalves[1] / 2);
  }
  if (best & 4) {
    W1gh = (_Float16*)alloc(whalves[2] / 2);
    W1gl = (_Float16*)alloc(whalves[2] / 2);
  }
  if (best & 8) {
    W1ch = (_Float16*)alloc(whalves[3] / 2);
    W1cl = (_Float16*)alloc(whalves[3] / 2);
  }

  adj_kernel<<<NN, 256, 0, stream>>>(E, Ah, Al);
  {
    // full zero: X1a (h-init) + Xz + Gl1 (t=0 reads diffused h0=0), contiguous
    size_t cbig8 = (size_t)2 * KPAD * (L1 + LZ + L1) / 8;
    zero_h8<<<(int)((cbig8 + 255) / 256), 256, 0, stream>>>(X1ah, cbig8);
    // Xs pad rows (rows NN..KPAD-1 feed gemm3 X-operand; must be finite-zero)
    size_t cpad8 = (size_t)(KPAD - NN) * LS / 8;
    zero_h8<<<(int)((cpad8 + 255) / 256), 256, 0, stream>>>(
        Xsh + (size_t)NN * LS, cpad8);
    zero_h8<<<(int)((cpad8 + 255) / 256), 256, 0, stream>>>(
        Xsl + (size_t)NN * LS, cpad8);
  }
  // Pre-loop: Gx = A @ Xs  (all 12 steps' x diffused, once)
  srcall_kernel<<<(NN * BB * TT + 255) / 256, 256, 0, stream>>>(src, Xsh, Xsl);
  mfma_gemm3<<<dim3(LS / 128, 7), 256, 0, stream>>>(Ah, Al, Xsh, Xsl, Gxh, Gxl, LS);
  // One-time W precompute for fitted flavors (kills per-step W-gen L2 storm)
  if (W0gh) wgen_pre<72, 65, 8, 32, 128><<<NN * 4, 256, 0, stream>>>(E, w0g, W0gh, W0gl);
  if (W0ch) wgen_pre<72, 65, 8, 32, 64><<<NN * 2, 256, 0, stream>>>(E, w0c, W0ch, W0cl);
  if (W1gh) wgen_pre<128, 128, 64, 32, 128><<<NN * 4, 256, 0, stream>>>(E, w1g, W1gh, W1gl);
  if (W1ch) wgen_pre<128, 128, 64, 32, 64><<<NN * 2, 256, 0, stream>>>(E, w1c, W1ch, W1cl);

  const int gx1 = L1 / 128;  // 64
  const int gxz = LZ / 128;  // 32
  // node-pair grid: 442 pairs padded to 448 (multiple of 8 for XCD swizzle)
  const int PQ = (((NN + 1) / 2 + 7) / 8) * 8;  // 448
  const int g_gate = PQ * 4;                    // C=4 chunks (OW=32, COUT=128)
  const int g_cand = PQ * 2;                    // C=2 chunks (OW=32, COUT=64)
  for (int t = 0; t < TT; ++t) {
    // ---- layer 0: identity x <- Xs[t], h0 <- X1a octets 0-7;
    //      diffused x <- Gx[t], diffused h0 <- Gl1 octets 0-7 (step t-1) ----
    if (W0gh)
      gconv_fused<72, 65, 8, 32, true, true><<<g_gate, 256, 0, stream>>>(
          Xsh, Xsl, LS, t, X1ah, X1al, L1, 0, Gxh, Gxl, LS, t, Gl1h, Gl1l, L1, 0,
          E, w0g, b0g, nullptr, X1ah, X1al, 0, ZR, Xzh, Xzl, 64, 0, W0gh, W0gl);
    else
      gconv_fused<72, 65, 8, 32, true, false><<<g_gate, 256, 0, stream>>>(
          Xsh, Xsl, LS, t, X1ah, X1al, L1, 0, Gxh, Gxl, LS, t, Gl1h, Gl1l, L1, 0,
          E, w0g, b0g, nullptr, X1ah, X1al, 0, ZR, Xzh, Xzl, 64, 0, nullptr, nullptr);
    mfma_gemm3<<<dim3(gxz, 7), 256, 0, stream>>>(Ah, Al, Xzh, Xzl, Gzh, Gzl, LZ);
    if (W0ch)
      gconv_fused<72, 65, 8, 32, false, true><<<g_cand, 256, 0, stream>>>(
          Xsh, Xsl, LS, t, Xzh, Xzl, LZ, 0, Gxh, Gxl, LS, t, Gzh, Gzl, LZ, 0,
          E, w0c, b0c, ZR, nullptr, nullptr, 0, nullptr, X1ah, X1al, 128, 0, W0ch, W0cl);
    else
      gconv_fused<72, 65, 8, 32, false, false><<<g_cand, 256, 0, stream>>>(
          Xsh, Xsl, LS, t, Xzh, Xzl, LZ, 0, Gxh, Gxl, LS, t, Gzh, Gzl, LZ, 0,
          E, w0c, b0c, ZR, nullptr, nullptr, 0, nullptr, X1ah, X1al, 128, 0, nullptr, nullptr);
    // ---- layer 1: identity h0 <- X1a oct 0-7, h1 <- X1a oct 8-15 ----
    mfma_gemm3<<<dim3(gx1, 7), 256, 0, stream>>>(Ah, Al, X1ah, X1al, Gl1h, Gl1l, L1);
    if (W1gh)
      gconv_fused<128, 128, 64, 32, true, true><<<g_gate, 256, 0, stream>>>(
          X1ah, X1al, L1, 0, X1ah, X1al, L1, 8, Gl1h, Gl1l, L1, 0, Gl1h, Gl1l, L1, 8,
          E, w1g, b1g, nullptr, X1ah, X1al, 64, ZR, Xzh, Xzl, 64, 0, W1gh, W1gl);
    else
      gconv_fused<128, 128, 64, 32, true, false><<<g_gate, 256, 0, stream>>>(
          X1ah, X1al, L1, 0, X1ah, X1al, L1, 8, Gl1h, Gl1l, L1, 0, Gl1h, Gl1l, L1, 8,
          E, w1g, b1g, nullptr, X1ah, X1al, 64, ZR, Xzh, Xzl, 64, 0, nullptr, nullptr);
    mfma_gemm3<<<dim3(gxz, 7), 256, 0, stream>>>(Ah, Al, Xzh, Xzl, Gzh, Gzl, LZ);
    if (W1ch)
      gconv_fused<128, 128, 64, 32, false, true><<<g_cand, 256, 0, stream>>>(
          X1ah, X1al, L1, 0, Xzh, Xzl, LZ, 0, Gl1h, Gl1l, L1, 0, Gzh, Gzl, LZ, 0,
          E, w1c, b1c, ZR, nullptr, nullptr, 0, nullptr, X1ah, X1al, 128, 64, W1ch, W1cl);
    else
      gconv_fused<128, 128, 64, 32, false, false><<<g_cand, 256, 0, stream>>>(
          X1ah, X1al, L1, 0, Xzh, Xzl, LZ, 0, Gl1h, Gl1l, L1, 0, Gzh, Gzl, LZ, 0,
          E, w1c, b1c, ZR, nullptr, nullptr, 0, nullptr, X1ah, X1al, 128, 64, nullptr, nullptr);
  }
  head_kernel<<<(BB * NN + 255) / 256, 256, 0, stream>>>(X1ah, X1al, cw, cb, out);
}

// Round 5
// 3403.791 us; speedup vs baseline: 1.1761x; 1.0445x over previous
//
#include <hip/hip_runtime.h>
#include <cstddef>

#define NN 883
#define BB 64
#define TT 12
#define EMB 10
#define KPAD 896  // node dim padded to multiple of 128

typedef short short8 __attribute__((ext_vector_type(8)));
typedef _Float16 half8 __attribute__((ext_vector_type(8)));
typedef float f32x4 __attribute__((ext_vector_type(4)));

__device__ __forceinline__ void split_f16(float v, _Float16* hp, _Float16* lp) {
  _Float16 h = (_Float16)v;
  *hp = h;
  *lp = (_Float16)(v - (float)h);
}

// -------- adjacency: A = softmax(relu(E E^T), axis=1), emitted as f16 hi/lo --
__global__ __launch_bounds__(256) void adj_kernel(const float* __restrict__ E,
                                                  _Float16* __restrict__ Ah,
                                                  _Float16* __restrict__ Al) {
  const int n = blockIdx.x;
  const int tid = threadIdx.x;
  __shared__ float sE[EMB];
  __shared__ float sred[256];
  if (tid < EMB) sE[tid] = E[n * EMB + tid];
  __syncthreads();
  float d[4];
  float lmax = 0.0f;
#pragma unroll
  for (int q = 0; q < 4; ++q) {
    int m = tid + q * 256;
    d[q] = 0.0f;
    if (m < NN) {
      float s = 0.0f;
#pragma unroll
      for (int e = 0; e < EMB; ++e) s += sE[e] * E[m * EMB + e];
      d[q] = fmaxf(s, 0.0f);
      lmax = fmaxf(lmax, d[q]);
    }
  }
  sred[tid] = lmax;
  __syncthreads();
  for (int s = 128; s > 0; s >>= 1) {
    if (tid < s) sred[tid] = fmaxf(sred[tid], sred[tid + s]);
    __syncthreads();
  }
  const float mx = sred[0];
  __syncthreads();
  float lsum = 0.0f;
#pragma unroll
  for (int q = 0; q < 4; ++q) {
    int m = tid + q * 256;
    if (m < NN) {
      d[q] = expf(d[q] - mx);
      lsum += d[q];
    }
  }
  sred[tid] = lsum;
  __syncthreads();
  for (int s = 128; s > 0; s >>= 1) {
    if (tid < s) sred[tid] += sred[tid + s];
    __syncthreads();
  }
  const float inv = 1.0f / sred[0];
#pragma unroll
  for (int q = 0; q < 4; ++q) {
    int m = tid + q * 256;
    if (m < KPAD) {
      float v = (m < NN) ? d[q] * inv : 0.0f;
      split_f16(v, &Ah[(size_t)n * KPAD + m], &Al[(size_t)n * KPAD + m]);
    }
  }
}

// -------- 3-term split-f16 MFMA GEMM; output written as split f16 ------------
__global__ __launch_bounds__(256) void mfma_gemm3(const _Float16* __restrict__ Ah,
                                                  const _Float16* __restrict__ Al,
                                                  const _Float16* __restrict__ Xh,
                                                  const _Float16* __restrict__ Xl,
                                                  _Float16* __restrict__ Gh,
                                                  _Float16* __restrict__ Gl, int L) {
  __shared__ _Float16 sA[2][128][40];
  __shared__ _Float16 sX[2][4][128][8];
  const int tid = threadIdx.x;
  const int lane = tid & 63;
  const int wid = tid >> 6;
  const int wm = (wid >> 1) * 64, wn = (wid & 1) * 64;
  const int bm = blockIdx.y * 128;
  const int bl = blockIdx.x * 128;
  const int l15 = lane & 15, l4 = lane >> 4;

  f32x4 acc[4][4] = {};

  const int xlp = (tid & 63) * 2;
  const int xko = tid >> 6;

  for (int k0 = 0; k0 < KPAD; k0 += 32) {
    __syncthreads();
#pragma unroll
    for (int p = 0; p < 2; ++p) {
      int i = tid + p * 256;
      int m = i >> 2, k8 = (i & 3) * 8;
      *(half8*)&sA[0][m][k8] = *(const half8*)&Ah[(size_t)(bm + m) * KPAD + k0 + k8];
      *(half8*)&sA[1][m][k8] = *(const half8*)&Al[(size_t)(bm + m) * KPAD + k0 + k8];
    }
    {
      int gl = bl + xlp;
      int kb = k0 + xko * 8;
#pragma unroll
      for (int buf = 0; buf < 2; ++buf) {
        const _Float16* Xp = buf ? Xl : Xh;
        unsigned int v[8];
#pragma unroll
        for (int j = 0; j < 8; ++j)
          v[j] = *(const unsigned int*)&Xp[(size_t)(kb + j) * L + gl];
        short8 lo, hi;
#pragma unroll
        for (int j = 0; j < 8; ++j) {
          lo[j] = (short)(v[j] & 0xFFFFu);
          hi[j] = (short)(v[j] >> 16);
        }
        *(short8*)&sX[buf][xko][xlp][0] = lo;
        *(short8*)&sX[buf][xko][xlp + 1][0] = hi;
      }
    }
    __syncthreads();
    half8 afh[4], afl[4], bfh[4], bfl[4];
#pragma unroll
    for (int mi = 0; mi < 4; ++mi) {
      afh[mi] = *(half8*)&sA[0][wm + mi * 16 + l15][l4 * 8];
      afl[mi] = *(half8*)&sA[1][wm + mi * 16 + l15][l4 * 8];
    }
#pragma unroll
    for (int ni = 0; ni < 4; ++ni) {
      bfh[ni] = *(half8*)&sX[0][l4][wn + ni * 16 + l15][0];
      bfl[ni] = *(half8*)&sX[1][l4][wn + ni * 16 + l15][0];
    }
#pragma unroll
    for (int mi = 0; mi < 4; ++mi)
#pragma unroll
      for (int ni = 0; ni < 4; ++ni) {
        acc[mi][ni] = __builtin_amdgcn_mfma_f32_16x16x32_f16(afh[mi], bfh[ni],
                                                             acc[mi][ni], 0, 0, 0);
        acc[mi][ni] = __builtin_amdgcn_mfma_f32_16x16x32_f16(afh[mi], bfl[ni],
                                                             acc[mi][ni], 0, 0, 0);
        acc[mi][ni] = __builtin_amdgcn_mfma_f32_16x16x32_f16(afl[mi], bfh[ni],
                                                             acc[mi][ni], 0, 0, 0);
      }
  }
#pragma unroll
  for (int mi = 0; mi < 4; ++mi) {
    int row0 = bm + wm + mi * 16 + l4 * 4;
#pragma unroll
    for (int ni = 0; ni < 4; ++ni) {
      int col = bl + wn + ni * 16 + l15;
#pragma unroll
      for (int r = 0; r < 4; ++r) {
        int row = row0 + r;
        if (row < NN)
          split_f16(acc[mi][ni][r], &Gh[(size_t)row * L + col],
                    &Gl[(size_t)row * L + col]);
      }
    }
  }
}

// -------- build compact Xs: [n][t*64+b] (DIN=1 -> no octet inflation) --------
__global__ __launch_bounds__(256) void srcall_kernel(const float* __restrict__ src,
                                                     _Float16* __restrict__ Xsh,
                                                     _Float16* __restrict__ Xsl) {
  int i = blockIdx.x * 256 + threadIdx.x;
  if (i >= NN * BB * TT) return;
  int b = i & 63;
  int rest = i >> 6;
  int t = rest % TT;
  int n = rest / TT;
  float v = src[((size_t)b * TT + t) * NN + n];
  size_t idx = (size_t)n * 768 + (size_t)t * 64 + b;
  split_f16(v, &Xsh[idx], &Xsl[idx]);
}

// -------- one-time per-node weight gen (t-invariant!) ------------------------
// Writes split-f16 weights in the gconv fragment layout:
// per (node n, o-chunk oc): [KOW][OW][8] halves, flat 16B-aligned.
template <int CS, int CIN, int XSPLIT, int OW, int COUT>
__global__ __launch_bounds__(256) void wgen_pre(const float* __restrict__ E,
                                                const float* __restrict__ wpool,
                                                _Float16* __restrict__ Wh,
                                                _Float16* __restrict__ Wl) {
  constexpr int C = COUT / OW;
  constexpr int KD = 2 * CS;
  constexpr int KOW = KD / 8;
  const int bid = blockIdx.x;
  const int n = bid / C;
  const int oc = bid % C;
  if (n >= NN) return;
  const int och = oc * OW;
  const int tid = threadIdx.x;
  __shared__ float sE[EMB];
  if (tid < EMB) sE[tid] = E[n * EMB + tid];
  __syncthreads();
  _Float16* bh = Wh + ((size_t)n * C + oc) * ((size_t)KOW * OW * 8);
  _Float16* bl = Wl + ((size_t)n * C + oc) * ((size_t)KOW * OW * 8);
  const int o = tid & (OW - 1);
  for (int ko = tid / OW; ko < KOW; ko += 256 / OW) {
    half8 hv, lv;
#pragma unroll
    for (int j = 0; j < 8; ++j) {
      const int k = ko * 8 + j;
      const int kk = (k >= CS) ? 1 : 0;
      const int kc = k - kk * CS;
      int ii;
      if (CS == CIN) ii = kc;
      else ii = (kc == 0) ? 0 : ((kc >= XSPLIT) ? kc - XSPLIT + 1 : -1);
      float w = 0.0f;
      if (ii >= 0) {
        const float* wp = wpool + ((size_t)kk * CIN + ii) * COUT + och + o;
#pragma unroll
        for (int d = 0; d < EMB; ++d)
          w += sE[d] * wp[(size_t)d * (2 * CIN * COUT)];
      }
      _Float16 hh = (_Float16)w;
      hv[j] = hh;
      lv[j] = (_Float16)(w - (float)hh);
    }
    *(half8*)&bh[((size_t)ko * OW + o) * 8] = hv;
    *(half8*)&bl[((size_t)ko * OW + o) * 8] = lv;
  }
}

// -------- fused per-node gconv, NODE-PAIR batched ---------------------------
// Two nodes per block (nA = 2p, nB = 2p+1); waves partition rows disjointly.
// h-state lives ONLY in X1a split-f16; epilogues reconstruct h = hi + lo.
// PRE=true: W fragments read DIRECTLY from precomputed global tiles in the
// k-loop (coalesced 256B per 16-lane group) -> no W LDS, no staging barrier.
// PRE=false: batched fused W-gen into LDS (wpool is L2-resident).
// CIX=true (layer 0): IX/DX are COMPACT [n][t*64+b] single-channel buffers
// (DIN=1); the k=0 octet fragment is synthesized in-register from a 2B load.
// Requires XSPLIT==8 (so kq<XSPLIT <=> kq==0, and kq-CS==0 in DX).
// GATE: z-half -> z*h into XA (=Xz); r-half -> ZRout.
// !GATE: GRU update written as split-f16 into XA (=X1a).
template <int CS, int CIN, int XSPLIT, int OW, bool GATE, bool PRE, bool CIX>
__global__ __launch_bounds__(256) void gconv_fused(
    const _Float16* __restrict__ IXh, const _Float16* __restrict__ IXl, int sIX, int oIX,
    const _Float16* __restrict__ IZh, const _Float16* __restrict__ IZl, int sIZ, int oIZ,
    const _Float16* __restrict__ DXh, const _Float16* __restrict__ DXl, int sDX, int oDX,
    const _Float16* __restrict__ DZh, const _Float16* __restrict__ DZl, int sDZ, int oDZ,
    const float* __restrict__ E, const float* __restrict__ wpool,
    const float* __restrict__ bpool, const float* __restrict__ ZRin,
    const _Float16* __restrict__ Hh, const _Float16* __restrict__ Hl, int hb,
    float* __restrict__ ZRout,
    _Float16* __restrict__ XAh, _Float16* __restrict__ XAl, int csA, int cbA,
    const _Float16* __restrict__ PWh, const _Float16* __restrict__ PWl) {
  constexpr int COUT = GATE ? 128 : 64;
  constexpr int C = COUT / OW;         // o-chunks per node
  constexpr int KD = 2 * CS;
  constexpr int KP = (KD + 31) & ~31;  // 160 / 256 (MFMA loop extent)
  constexpr int KOW = KD / 8;          // 18 / 32 (W octets actually stored)
  // XCD swizzle decode over node-pairs
  const int bid = blockIdx.x;
  const int xcd = bid & 7;
  const int rest = bid >> 3;
  const int oc = rest % C;
  const int pq = rest / C;
  const int p = pq * 8 + xcd;
  const int nA = p * 2;
  if (nA >= NN) return;
  const int och = oc * OW;
  const int tid = threadIdx.x;
  const int lane = tid & 63, wid = tid >> 6;
  const int ns = wid >> 1;          // wave's node slot (0/1)
  const int wm = (wid & 1) * 32;    // row half within node
  const int l15 = lane & 15, l4 = lane >> 4;
  const int myn = nA + ns;          // may be >= NN for odd tail
  const int anode = (myn < NN) ? myn : nA;  // safe address node

  __shared__ float sE[2][EMB];
  __shared__ float sB[2][OW];
  __shared__ _Float16 sWh[PRE ? 8 : 2 * KOW * OW * 8];
  __shared__ _Float16 sWl[PRE ? 8 : 2 * KOW * OW * 8];

  if (tid < 2 * EMB) {
    const int s = tid / EMB, d = tid - s * EMB;
    const int node = nA + s;
    sE[s][d] = (node < NN) ? E[node * EMB + d] : 0.0f;
  }
  __syncthreads();

  // ---- W (regen fallback only): batched fused gen into LDS ------------------
  if constexpr (!PRE) {
    const int o = tid & (OW - 1);
    for (int ko = tid / OW; ko < KOW; ko += 256 / OW) {
      half8 hv0, lv0, hv1, lv1;
#pragma unroll
      for (int j = 0; j < 8; ++j) {
        const int k = ko * 8 + j;
        const int kk = (k >= CS) ? 1 : 0;
        const int kc = k - kk * CS;
        int ii;
        if (CS == CIN) ii = kc;
        else ii = (kc == 0) ? 0 : ((kc >= XSPLIT) ? kc - XSPLIT + 1 : -1);
        float w0 = 0.0f, w1 = 0.0f;
        if (ii >= 0) {
          const float* wp = wpool + ((size_t)kk * CIN + ii) * COUT + och + o;
#pragma unroll
          for (int d = 0; d < EMB; ++d) {
            const float wv = wp[(size_t)d * (2 * CIN * COUT)];
            w0 += sE[0][d] * wv;
            w1 += sE[1][d] * wv;
          }
        }
        _Float16 h0 = (_Float16)w0;
        hv0[j] = h0;
        lv0[j] = (_Float16)(w0 - (float)h0);
        _Float16 h1 = (_Float16)w1;
        hv1[j] = h1;
        lv1[j] = (_Float16)(w1 - (float)h1);
      }
      *(half8*)&sWh[((size_t)ko * OW + o) * 8] = hv0;
      *(half8*)&sWl[((size_t)ko * OW + o) * 8] = lv0;
      *(half8*)&sWh[(size_t)KOW * OW * 8 + ((size_t)ko * OW + o) * 8] = hv1;
      *(half8*)&sWl[(size_t)KOW * OW * 8 + ((size_t)ko * OW + o) * 8] = lv1;
    }
  }
  if (tid < 2 * OW) {
    const int s = tid / OW, o = tid - s * OW;
    float bb = 0.0f;
#pragma unroll
    for (int d = 0; d < EMB; ++d) bb += sE[s][d] * bpool[d * COUT + och + o];
    sB[s][o] = bb;
  }
  __syncthreads();

  // ---- MFMA: per-wave node, A-fragments coalesced half8 from global ---------
  const size_t bIX = CIX ? ((size_t)anode * sIX + (size_t)oIX * 64)
                         : ((size_t)anode * sIX + (size_t)oIX * 512);
  const size_t bIZ = (size_t)anode * sIZ + (size_t)oIZ * 512;
  const size_t bDX = CIX ? ((size_t)anode * sDX + (size_t)oDX * 64)
                         : ((size_t)anode * sDX + (size_t)oDX * 512);
  const size_t bDZ = (size_t)anode * sDZ + (size_t)oDZ * 512;
  const size_t wtile = (size_t)KOW * OW * 8;
  const size_t wbase = PRE ? ((size_t)anode * C + oc) * wtile : (size_t)ns * wtile;
  f32x4 acc[2][2] = {};
  for (int k0 = 0; k0 < KP; k0 += 32) {
    const int kq = k0 + l4 * 8;
    half8 ah[2], al[2];
#pragma unroll
    for (int mt = 0; mt < 2; ++mt) {
      const int b = wm + mt * 16 + l15;
      if (kq < XSPLIT) {
        if constexpr (CIX) {  // compact: kq==0, single channel at [b]
          half8 hv = (half8)(_Float16)0.f, lv = (half8)(_Float16)0.f;
          const size_t o = bIX + (size_t)b;
          hv[0] = IXh[o];
          lv[0] = IXl[o];
          ah[mt] = hv;
          al[mt] = lv;
        } else {
          const size_t o = bIX + (size_t)(kq >> 3) * 512 + (size_t)b * 8;
          ah[mt] = *(const half8*)&IXh[o];
          al[mt] = *(const half8*)&IXl[o];
        }
      } else if (kq < CS) {
        const size_t o = bIZ + (size_t)((kq - XSPLIT) >> 3) * 512 + (size_t)b * 8;
        ah[mt] = *(const half8*)&IZh[o];
        al[mt] = *(const half8*)&IZl[o];
      } else if (kq < CS + XSPLIT) {
        if constexpr (CIX) {  // compact diffused x: kq-CS==0
          half8 hv = (half8)(_Float16)0.f, lv = (half8)(_Float16)0.f;
          const size_t o = bDX + (size_t)b;
          hv[0] = DXh[o];
          lv[0] = DXl[o];
          ah[mt] = hv;
          al[mt] = lv;
        } else {
          const size_t o = bDX + (size_t)((kq - CS) >> 3) * 512 + (size_t)b * 8;
          ah[mt] = *(const half8*)&DXh[o];
          al[mt] = *(const half8*)&DXl[o];
        }
      } else if (kq < KD) {
        const size_t o =
            bDZ + (size_t)((kq - CS - XSPLIT) >> 3) * 512 + (size_t)b * 8;
        ah[mt] = *(const half8*)&DZh[o];
        al[mt] = *(const half8*)&DZl[o];
      } else {
        ah[mt] = (half8)(_Float16)0.f;
        al[mt] = (half8)(_Float16)0.f;
      }
    }
    const int koi = kq >> 3;
    half8 bh[2], bl[2];
#pragma unroll
    for (int nt = 0; nt < 2; ++nt) {
      const int ol = nt * 16 + l15;
      if (KP == KD || kq < KD) {
        const size_t wo = wbase + ((size_t)koi * OW + ol) * 8;
        if constexpr (PRE) {
          bh[nt] = *(const half8*)&PWh[wo];
          bl[nt] = *(const half8*)&PWl[wo];
        } else {
          bh[nt] = *(const half8*)&sWh[wo];
          bl[nt] = *(const half8*)&sWl[wo];
        }
      } else {
        bh[nt] = (half8)(_Float16)0.f;
        bl[nt] = (half8)(_Float16)0.f;
      }
    }
#pragma unroll
    for (int mt = 0; mt < 2; ++mt)
#pragma unroll
      for (int nt = 0; nt < 2; ++nt) {
        acc[mt][nt] =
            __builtin_amdgcn_mfma_f32_16x16x32_f16(ah[mt], bh[nt], acc[mt][nt], 0, 0, 0);
        acc[mt][nt] =
            __builtin_amdgcn_mfma_f32_16x16x32_f16(ah[mt], bl[nt], acc[mt][nt], 0, 0, 0);
        acc[mt][nt] =
            __builtin_amdgcn_mfma_f32_16x16x32_f16(al[mt], bh[nt], acc[mt][nt], 0, 0, 0);
      }
  }

  // ---- epilogue (octet-major writes; h reconstructed from split-f16) --------
  if (myn < NN) {
#pragma unroll
    for (int mt = 0; mt < 2; ++mt) {
#pragma unroll
      for (int nt = 0; nt < 2; ++nt) {
        const int ol = nt * 16 + l15;
        const int og = och + ol;  // global output channel
        const float bias = sB[ns][ol];
#pragma unroll
        for (int r = 0; r < 4; ++r) {
          const int b = wm + mt * 16 + l4 * 4 + r;
          const size_t nb = (size_t)myn * 64 + b;
          const float v = acc[mt][nt][r] + bias;
          if constexpr (GATE) {
            const float s = 1.0f / (1.0f + expf(-v));
            if (og < 64) {  // z half: write z*h compact (cand GEMM input)
              const int ch = hb + og;
              const size_t ih = (size_t)myn * 8192 + (size_t)(ch >> 3) * 512 +
                                (size_t)b * 8 + (ch & 7);
              const float hold = (float)Hh[ih] + (float)Hl[ih];
              const float zh = s * hold;
              const int c2 = cbA + og;
              size_t ia = (size_t)myn * 64 * csA + (size_t)(c2 >> 3) * 512 +
                          (size_t)b * 8 + (c2 & 7);
              split_f16(zh, &XAh[ia], &XAl[ia]);
            } else {  // r half
              ZRout[nb * 64 + (og - 64)] = s;
            }
          } else {
            const float hc = tanhf(v);
            const float rr = ZRin[nb * 64 + og];
            const int cA = cbA + og;
            const size_t ia = (size_t)myn * 64 * csA + (size_t)(cA >> 3) * 512 +
                              (size_t)b * 8 + (cA & 7);
            const float hold = (float)XAh[ia] + (float)XAl[ia];
            const float hn = rr * hold + (1.0f - rr) * hc;
            split_f16(hn, &XAh[ia], &XAl[ia]);
          }
        }
      }
    }
  }
}

// ---------------- output head (h1 from X1a octets 8-15) ----------------------
__global__ __launch_bounds__(256) void head_kernel(const _Float16* __restrict__ Hh,
                                                   const _Float16* __restrict__ Hl,
                                                   const float* __restrict__ cw,
                                                   const float* __restrict__ cb,
                                                   float* __restrict__ out) {
  int i = blockIdx.x * 256 + threadIdx.x;
  if (i >= BB * NN) return;
  int n = i % NN, b = i / NN;
  float hv[64];
#pragma unroll
  for (int j = 0; j < 64; ++j) {
    const int c = 64 + j;
    const size_t ia =
        (size_t)n * 8192 + (size_t)(c >> 3) * 512 + (size_t)b * 8 + (c & 7);
    hv[j] = (float)Hh[ia] + (float)Hl[ia];
  }
  for (int o = 0; o < 12; ++o) {
    float s = cb[o];
#pragma unroll
    for (int j = 0; j < 64; ++j) s += hv[j] * cw[o * 64 + j];
    out[((size_t)b * 12 + o) * NN + n] = s;
  }
}

// 16B-per-thread zero (count in half8 units)
__global__ __launch_bounds__(256) void zero_h8(_Float16* __restrict__ p,
                                               size_t cnt8) {
  size_t i = (size_t)blockIdx.x * 256 + threadIdx.x;
  if (i < cnt8) *(half8*)&p[i * 8] = (half8)(_Float16)0.f;
}

extern "C" void kernel_launch(void* const* d_in, const int* in_sizes, int n_in,
                              void* d_out, int out_size, void* d_ws, size_t ws_size,
                              hipStream_t stream) {
  const float* src = (const float*)d_in[0];
  const float* E = (const float*)d_in[1];
  const float* w0g = (const float*)d_in[2];
  const float* b0g = (const float*)d_in[3];
  const float* w0c = (const float*)d_in[4];
  const float* b0c = (const float*)d_in[5];
  const float* w1g = (const float*)d_in[6];
  const float* b1g = (const float*)d_in[7];
  const float* w1c = (const float*)d_in[8];
  const float* b1c = (const float*)d_in[9];
  const float* cw = (const float*)d_in[10];
  const float* cb = (const float*)d_in[11];
  float* out = (float*)d_out;
  float* ws = (float*)d_ws;

  size_t off = 0;
  auto alloc = [&](size_t cnt) {  // cnt in floats
    float* p = ws + off;
    off += (cnt + 63) & ~(size_t)63;
    return p;
  };
  const int LC = TT * 64;   // 768 compact x columns (t*64+b)
  const int L1 = 64 * 128;  // 8192 (16 octets)
  const int LZ = 64 * 64;   // 4096 (8 octets)
  _Float16* Ah = (_Float16*)alloc((size_t)KPAD * KPAD / 2);
  _Float16* Al = (_Float16*)alloc((size_t)KPAD * KPAD / 2);
  // compact x buffers (DIN=1): [n][t*64+b]
  _Float16* Xsh = (_Float16*)alloc((size_t)KPAD * LC / 2);
  _Float16* Xsl = (_Float16*)alloc((size_t)KPAD * LC / 2);
  _Float16* Gxh = (_Float16*)alloc((size_t)KPAD * LC / 2);
  _Float16* Gxl = (_Float16*)alloc((size_t)KPAD * LC / 2);
  // contiguous zero span: X1a, Xz, Gl1 (hi/lo pairs)
  _Float16* X1ah = (_Float16*)alloc((size_t)KPAD * L1 / 2);
  _Float16* X1al = (_Float16*)alloc((size_t)KPAD * L1 / 2);
  _Float16* Xzh = (_Float16*)alloc((size_t)KPAD * LZ / 2);
  _Float16* Xzl = (_Float16*)alloc((size_t)KPAD * LZ / 2);
  _Float16* Gl1h = (_Float16*)alloc((size_t)KPAD * L1 / 2);
  _Float16* Gl1l = (_Float16*)alloc((size_t)KPAD * L1 / 2);
  _Float16* Gzh = (_Float16*)alloc((size_t)KPAD * LZ / 2);
  _Float16* Gzl = (_Float16*)alloc((size_t)KPAD * LZ / 2);
  float* ZR = alloc((size_t)NN * BB * 64);
  if (off * sizeof(float) > ws_size) return;  // ws too small: fail loud (zeros)

  // ---- tiered precomputed per-node weights (t-invariant) ----
  // Flavor f cost (floats): g0 NN*18432, c0 NN*9216, g1 NN*32768, c1 NN*16384.
  // Enumerate all 16 subsets, pick max total that fits (graceful degradation).
  // Compact Xs/Gx freed ~38MB vs r4 -> more flavors fit.
  const size_t wsfl = ws_size / sizeof(float);
  const size_t whalves[4] = {(size_t)NN * 18432, (size_t)NN * 9216,
                             (size_t)NN * 32768, (size_t)NN * 16384};
  const size_t avail = (wsfl > off) ? (wsfl - off) : 0;
  int best = 0;
  size_t bestsz = 0;
  for (int s = 1; s < 16; ++s) {
    size_t tot = 0;
    for (int f = 0; f < 4; ++f)
      if (s & (1 << f)) tot += whalves[f] + 128;  // +alignment slack
    if (tot <= avail && tot > bestsz) {
      bestsz = tot;
      best = s;
    }
  }
  _Float16 *W0gh = nullptr, *W0gl = nullptr, *W0ch = nullptr, *W0cl = nullptr;
  _Float16 *W1gh = nullptr, *W1gl = nullptr, *W1ch = nullptr, *W1cl = nullptr;
  if (best & 1) {
    W0gh = (_Float16*)alloc(whalves[0] / 2);
    W0gl = (_Float16*)alloc(whalves[0] / 2);
  }
  if (best & 2) {
    W0ch = (_Float16*)alloc(whalves[1] / 2);
    W0cl = (_Float16*)alloc(whalves[1] / 2);
  }
  if (best & 4) {
    W1gh = (_Float16*)alloc(whalves[2] / 2);
    W1gl = (_Float16*)alloc(whalves[2] / 2);
  }
  if (best & 8) {
    W1ch = (_Float16*)alloc(whalves[3] / 2);
    W1cl = (_Float16*)alloc(whalves[3] / 2);
  }

  adj_kernel<<<NN, 256, 0, stream>>>(E, Ah, Al);
  {
    // full zero: X1a (h-init) + Xz + Gl1 (t=0 reads diffused h0=0), contiguous
    size_t cbig8 = (size_t)2 * KPAD * (L1 + LZ + L1) / 8;
    zero_h8<<<(int)((cbig8 + 255) / 256), 256, 0, stream>>>(X1ah, cbig8);
    // compact Xs pad rows (rows NN..KPAD-1 feed gemm3 X-operand; NaN-poison!)
    size_t cpad8 = (size_t)(KPAD - NN) * LC / 8;
    zero_h8<<<(int)((cpad8 + 255) / 256), 256, 0, stream>>>(
        Xsh + (size_t)NN * LC, cpad8);
    zero_h8<<<(int)((cpad8 + 255) / 256), 256, 0, stream>>>(
        Xsl + (size_t)NN * LC, cpad8);
  }
  // Pre-loop: Gx = A @ Xs (compact, L=768; all 12 steps diffused at once)
  srcall_kernel<<<(NN * BB * TT + 255) / 256, 256, 0, stream>>>(src, Xsh, Xsl);
  mfma_gemm3<<<dim3(LC / 128, 7), 256, 0, stream>>>(Ah, Al, Xsh, Xsl, Gxh, Gxl, LC);
  // One-time W precompute for fitted flavors (kills per-step W-gen L2 storm)
  if (W0gh) wgen_pre<72, 65, 8, 32, 128><<<NN * 4, 256, 0, stream>>>(E, w0g, W0gh, W0gl);
  if (W0ch) wgen_pre<72, 65, 8, 32, 64><<<NN * 2, 256, 0, stream>>>(E, w0c, W0ch, W0cl);
  if (W1gh) wgen_pre<128, 128, 64, 32, 128><<<NN * 4, 256, 0, stream>>>(E, w1g, W1gh, W1gl);
  if (W1ch) wgen_pre<128, 128, 64, 32, 64><<<NN * 2, 256, 0, stream>>>(E, w1c, W1ch, W1cl);

  const int gx1 = L1 / 128;  // 64
  const int gxz = LZ / 128;  // 32
  // node-pair grid: 442 pairs padded to 448 (multiple of 8 for XCD swizzle)
  const int PQ = (((NN + 1) / 2 + 7) / 8) * 8;  // 448
  const int g_gate = PQ * 4;                    // C=4 chunks (OW=32, COUT=128)
  const int g_cand = PQ * 2;                    // C=2 chunks (OW=32, COUT=64)
  for (int t = 0; t < TT; ++t) {
    // ---- layer 0: identity x <- Xs[t] (compact), h0 <- X1a octets 0-7;
    //      diffused x <- Gx[t] (compact), diffused h0 <- Gl1 oct 0-7 ----
    if (W0gh)
      gconv_fused<72, 65, 8, 32, true, true, true><<<g_gate, 256, 0, stream>>>(
          Xsh, Xsl, LC, t, X1ah, X1al, L1, 0, Gxh, Gxl, LC, t, Gl1h, Gl1l, L1, 0,
          E, w0g, b0g, nullptr, X1ah, X1al, 0, ZR, Xzh, Xzl, 64, 0, W0gh, W0gl);
    else
      gconv_fused<72, 65, 8, 32, true, false, true><<<g_gate, 256, 0, stream>>>(
          Xsh, Xsl, LC, t, X1ah, X1al, L1, 0, Gxh, Gxl, LC, t, Gl1h, Gl1l, L1, 0,
          E, w0g, b0g, nullptr, X1ah, X1al, 0, ZR, Xzh, Xzl, 64, 0, nullptr, nullptr);
    mfma_gemm3<<<dim3(gxz, 7), 256, 0, stream>>>(Ah, Al, Xzh, Xzl, Gzh, Gzl, LZ);
    if (W0ch)
      gconv_fused<72, 65, 8, 32, false, true, true><<<g_cand, 256, 0, stream>>>(
          Xsh, Xsl, LC, t, Xzh, Xzl, LZ, 0, Gxh, Gxl, LC, t, Gzh, Gzl, LZ, 0,
          E, w0c, b0c, ZR, nullptr, nullptr, 0, nullptr, X1ah, X1al, 128, 0, W0ch, W0cl);
    else
      gconv_fused<72, 65, 8, 32, false, false, true><<<g_cand, 256, 0, stream>>>(
          Xsh, Xsl, LC, t, Xzh, Xzl, LZ, 0, Gxh, Gxl, LC, t, Gzh, Gzl, LZ, 0,
          E, w0c, b0c, ZR, nullptr, nullptr, 0, nullptr, X1ah, X1al, 128, 0, nullptr, nullptr);
    // ---- layer 1: identity h0 <- X1a oct 0-7, h1 <- X1a oct 8-15 ----
    mfma_gemm3<<<dim3(gx1, 7), 256, 0, stream>>>(Ah, Al, X1ah, X1al, Gl1h, Gl1l, L1);
    if (W1gh)
      gconv_fused<128, 128, 64, 32, true, true, false><<<g_gate, 256, 0, stream>>>(
          X1ah, X1al, L1, 0, X1ah, X1al, L1, 8, Gl1h, Gl1l, L1, 0, Gl1h, Gl1l, L1, 8,
          E, w1g, b1g, nullptr, X1ah, X1al, 64, ZR, Xzh, Xzl, 64, 0, W1gh, W1gl);
    else
      gconv_fused<128, 128, 64, 32, true, false, false><<<g_gate, 256, 0, stream>>>(
          X1ah, X1al, L1, 0, X1ah, X1al, L1, 8, Gl1h, Gl1l, L1, 0, Gl1h, Gl1l, L1, 8,
          E, w1g, b1g, nullptr, X1ah, X1al, 64, ZR, Xzh, Xzl, 64, 0, nullptr, nullptr);
    mfma_gemm3<<<dim3(gxz, 7), 256, 0, stream>>>(Ah, Al, Xzh, Xzl, Gzh, Gzl, LZ);
    if (W1ch)
      gconv_fused<128, 128, 64, 32, false, true, false><<<g_cand, 256, 0, stream>>>(
          X1ah, X1al, L1, 0, Xzh, Xzl, LZ, 0, Gl1h, Gl1l, L1, 0, Gzh, Gzl, LZ, 0,
          E, w1c, b1c, ZR, nullptr, nullptr, 0, nullptr, X1ah, X1al, 128, 64, W1ch, W1cl);
    else
      gconv_fused<128, 128, 64, 32, false, false, false><<<g_cand, 256, 0, stream>>>(
          X1ah, X1al, L1, 0, Xzh, Xzl, LZ, 0, Gl1h, Gl1l, L1, 0, Gzh, Gzl, LZ, 0,
          E, w1c, b1c, ZR, nullptr, nullptr, 0, nullptr, X1ah, X1al, 128, 64, nullptr, nullptr);
  }
  head_kernel<<<(BB * NN + 255) / 256, 256, 0, stream>>>(X1ah, X1al, cw, cb, out);
}